// Round 11
// baseline (4194.316 us; speedup 1.0000x reference)
//
#include <hip/hip_runtime.h>
#include <stdint.h>

typedef __attribute__((ext_vector_type(8))) short short8;
typedef __attribute__((ext_vector_type(4))) float f32x4;
typedef __attribute__((ext_vector_type(4))) unsigned int u32x4;

#define B_    32
#define T_    512
#define E_    300
#define KE_   384     // padded embed K (multiple of 128 for 4-wave x 32 split)
#define H_    1024
#define G4_   4096
#define R_    30
#define AD_   350
#define AC_   384
#define MH_   512
#define FEAT_ 61440
#define NWG_  64      // workgroups per direction
#define NU_   16      // hidden units per workgroup

__device__ __forceinline__ unsigned short f2bu(float f) {
  unsigned int x = __builtin_bit_cast(unsigned int, f);
  x += 0x7fffu + ((x >> 16) & 1u);
  return (unsigned short)(x >> 16);
}
__device__ __forceinline__ float b2f(unsigned short u) {
  return __builtin_bit_cast(float, (unsigned int)u << 16);
}
__device__ __forceinline__ float sigm(float x) {
  return __builtin_amdgcn_rcpf(1.f + __expf(-x));
}
__device__ __forceinline__ float tanh_fast(float x) {
  return 1.f - 2.f * __builtin_amdgcn_rcpf(1.f + __expf(2.f * x));
}

// 16x dwordx4 bulk load of the two 512B h rows, FL = cache flags
#define BULK16(a0p, a1p, FL)                                                    \
  asm volatile(                                                                 \
      "global_load_dwordx4 %0, %16, off " FL "\n\t"                             \
      "global_load_dwordx4 %1, %16, off offset:64 " FL "\n\t"                   \
      "global_load_dwordx4 %2, %16, off offset:128 " FL "\n\t"                  \
      "global_load_dwordx4 %3, %16, off offset:192 " FL "\n\t"                  \
      "global_load_dwordx4 %4, %16, off offset:256 " FL "\n\t"                  \
      "global_load_dwordx4 %5, %16, off offset:320 " FL "\n\t"                  \
      "global_load_dwordx4 %6, %16, off offset:384 " FL "\n\t"                  \
      "global_load_dwordx4 %7, %16, off offset:448 " FL "\n\t"                  \
      "global_load_dwordx4 %8, %17, off " FL "\n\t"                             \
      "global_load_dwordx4 %9, %17, off offset:64 " FL "\n\t"                   \
      "global_load_dwordx4 %10, %17, off offset:128 " FL "\n\t"                 \
      "global_load_dwordx4 %11, %17, off offset:192 " FL "\n\t"                 \
      "global_load_dwordx4 %12, %17, off offset:256 " FL "\n\t"                 \
      "global_load_dwordx4 %13, %17, off offset:320 " FL "\n\t"                 \
      "global_load_dwordx4 %14, %17, off offset:384 " FL "\n\t"                 \
      "global_load_dwordx4 %15, %17, off offset:448 " FL "\n\t"                 \
      "s_waitcnt vmcnt(0)"                                                      \
      : "=&v"(q0), "=&v"(q1), "=&v"(q2), "=&v"(q3), "=&v"(q4), "=&v"(q5),       \
        "=&v"(q6), "=&v"(q7), "=&v"(q8), "=&v"(q9), "=&v"(qa), "=&v"(qb),       \
        "=&v"(qc), "=&v"(qd), "=&v"(qe), "=&v"(qf)                              \
      : "v"(a0p), "v"(a1p)                                                      \
      : "memory")

// validate: any bf16 half with bit14 set => sentinel/unwritten
#define VAL16(BAD)                                                              \
  {                                                                             \
    u32x4 o01 = q0 | q1, o23 = q2 | q3, o45 = q4 | q5, o67 = q6 | q7;           \
    u32x4 o89 = q8 | q9, oab = qa | qb, ocd = qc | qd, oef = qe | qf;           \
    u32x4 ov4 = ((o01 | o23) | (o45 | o67)) | ((o89 | oab) | (ocd | oef));      \
    unsigned ovv = (ov4[0] | ov4[1]) | (ov4[2] | ov4[3]);                       \
    BAD = (ovv & 0x40004000u) != 0;                                             \
  }

// ---------------------------------------------------------------------------
// K0: cast/pad to bf16: xb[16384][384], wihb[8192][384], w1b[384][2048],
//     wmlpb[512][61440]
// ---------------------------------------------------------------------------
__global__ void k0_prep(const int* __restrict__ inp, const float* __restrict__ W_emb,
                        const float* __restrict__ W_ih, const float* __restrict__ W1,
                        const float* __restrict__ W_mlp,
                        unsigned short* __restrict__ xb, unsigned short* __restrict__ wihb,
                        unsigned short* __restrict__ w1b, unsigned short* __restrict__ wmlpb) {
  const int N1 = 16384 * KE_;
  const int N2 = 8192 * KE_;
  const int N3 = AC_ * 2048;
  const int N4 = MH_ * FEAT_;
  const int NT = N1 + N2 + N3 + N4;
  for (int i = blockIdx.x * blockDim.x + threadIdx.x; i < NT; i += gridDim.x * blockDim.x) {
    if (i < N1) {
      int row = i / KE_, e = i - row * KE_;
      float v = (e < E_) ? W_emb[(size_t)inp[row] * E_ + e] : 0.f;
      xb[i] = f2bu(v);
    } else if (i < N1 + N2) {
      int j = i - N1;
      int rw = j / KE_, e = j - rw * KE_;
      float v = (e < E_) ? W_ih[(size_t)rw * E_ + e] : 0.f;
      wihb[j] = f2bu(v);
    } else if (i < N1 + N2 + N3) {
      int j = i - N1 - N2;
      int a = j >> 11, k = j & 2047;
      float v = (a < AD_) ? W1[(size_t)a * 2048 + k] : 0.f;
      w1b[j] = f2bu(v);
    } else {
      int j = i - N1 - N2 - N3;
      wmlpb[j] = f2bu(W_mlp[j]);
    }
  }
}

// ---------------------------------------------------------------------------
// K2 v11: persistent bidirectional LSTM, XCD-local rendezvous with sc0
//   write-through publication (fixes R7's plain-store lazy-visibility).
//   - XCC_ID role claim: XCD0 -> dir0, XCD1 -> dir1, XCDs 2-7 delayed
//     backstop claimers.  Placement heuristic only, never correctness.
//   - producer dual-publish: sc0 store -> own XCD L2 (fast, coherent for
//     same-XCD readers) + sc0 sc1 store -> MALL mirror (global visibility)
//   - consumer fast path: sc0 thin poll (64-iter bound) + sc0 payload/retry
//     on outb; miss -> mirror path (sc0 sc1 on outm) this step; 8 straight
//     misses latch mirror mode permanently.
// ---------------------------------------------------------------------------
__global__ __launch_bounds__(256, 1) void k2_rnn(const float* __restrict__ Whh,
                                                 const unsigned short* __restrict__ wihb,
                                                 const unsigned short* __restrict__ xb,
                                                 const float* __restrict__ b_ih,
                                                 const float* __restrict__ b_hh,
                                                 unsigned short* __restrict__ outb,
                                                 unsigned short* __restrict__ outm,
                                                 int* __restrict__ pool) {
  const int tid = threadIdx.x;
  int xcc;
  asm volatile("s_getreg_b32 %0, hwreg(HW_REG_XCC_ID)" : "=s"(xcc));

  __shared__ int rs[2];
  if (tid == 0) {
    int d = -1, r = -1;
    if (xcc == 0 || xcc == 1) {
      d = xcc;
      r = atomicAdd(&pool[d], 1);
      if (r >= NWG_) { d = -1; r = -1; }
    } else {
      // backstop: let local claimers go first (~80us), then fill leftovers
      for (int i = 0; i < 48; ++i) __builtin_amdgcn_s_sleep(63);
      if (__hip_atomic_load(&pool[0], __ATOMIC_RELAXED, __HIP_MEMORY_SCOPE_AGENT) < NWG_) {
        r = atomicAdd(&pool[0], 1); d = 0;
        if (r >= NWG_) { r = -1; d = -1; }
      }
      if (r < 0 && __hip_atomic_load(&pool[1], __ATOMIC_RELAXED, __HIP_MEMORY_SCOPE_AGENT) < NWG_) {
        r = atomicAdd(&pool[1], 1); d = 1;
        if (r >= NWG_) { r = -1; d = -1; }
      }
    }
    rs[0] = d; rs[1] = r;
  }
  __syncthreads();
  const int dir = rs[0];
  const int w = rs[1];
  if (dir < 0) return;

  const int wid = tid >> 6, lane = tid & 63;
  const int l15 = lane & 15, lg = lane >> 4;

  __shared__ float Gp[4][4][32][21];               // [wave][gate][batch][unit+pad21]
  __shared__ __align__(16) unsigned short htmp[32][16];

  // ---- preload W_hh K-quarter as bf16 A-frags --------------------------
  short8 afr[4][8];
  {
    const int kq = wid << 8;
#pragma unroll
    for (int g = 0; g < 4; ++g) {
      const float* wp = Whh + ((size_t)dir * G4_ + g * H_ + w * NU_ + l15) * H_ + kq + lg * 8;
#pragma unroll
      for (int ktl = 0; ktl < 8; ++ktl) {
        float4 f0 = *(const float4*)(wp + ktl * 32);
        float4 f1 = *(const float4*)(wp + ktl * 32 + 4);
        short8 s;
        s[0] = (short)f2bu(f0.x); s[1] = (short)f2bu(f0.y);
        s[2] = (short)f2bu(f0.z); s[3] = (short)f2bu(f0.w);
        s[4] = (short)f2bu(f1.x); s[5] = (short)f2bu(f1.y);
        s[6] = (short)f2bu(f1.z); s[7] = (short)f2bu(f1.w);
        afr[g][ktl] = s;
      }
    }
  }

  // ---- preload W_ih K-slice (96 of 384) as bf16 A-frags ----------------
  const int kqx = wid * 96;
  short8 axr[4][3];
#pragma unroll
  for (int g = 0; g < 4; ++g) {
    const unsigned short* xp = wihb + ((size_t)dir * G4_ + g * H_ + w * NU_ + l15) * KE_ + kqx + lg * 8;
#pragma unroll
    for (int kt = 0; kt < 3; ++kt) axr[g][kt] = *(const short8*)(xp + kt * 32);
  }

  const int u = tid >> 5;    // activation role: unit pair (u, u+8)
  const int b = tid & 31;    // activation role: batch

  float bsum[2][4];
#pragma unroll
  for (int p = 0; p < 2; ++p)
#pragma unroll
    for (int g = 0; g < 4; ++g) {
      int row = dir * G4_ + g * H_ + w * NU_ + u + p * 8;
      bsum[p][g] = b_ih[row] + b_hh[row];
    }

  // payload/poll base pointers (local outb + MALL mirror outm)
  const size_t po0 = (size_t)l15 * T_ * 2048 + dir * H_ + (wid << 8) + lg * 8;
  const size_t po1 = (size_t)(l15 + 16) * T_ * 2048 + dir * H_ + (wid << 8) + lg * 8;
  const unsigned short* rb0 = outb + po0;
  const unsigned short* rb1 = outb + po1;
  const unsigned short* rm0 = outm + po0;
  const unsigned short* rm1 = outm + po1;
  const size_t polloff = (size_t)dir * H_ + ((wid << 4) + l15) * NU_;
  const unsigned short* pbL = outb + polloff;
  const unsigned short* pbM = outm + polloff;

  float cst[2] = {0.f, 0.f};
  int mirror = 0, strikes = 0;

#pragma unroll 1
  for (int s = 0; s < T_; ++s) {
    const int t = dir ? (T_ - 1 - s) : s;

    f32x4 acc[4][2];
#pragma unroll
    for (int g = 0; g < 4; ++g) {
      acc[g][0] = (f32x4){0.f, 0.f, 0.f, 0.f};
      acc[g][1] = (f32x4){0.f, 0.f, 0.f, 0.f};
    }

    // -- x-GEMM: independent of h; fills the publish-to-visible window ---
    {
      short8 xbf[2][3];
#pragma unroll
      for (int n = 0; n < 2; ++n)
#pragma unroll
        for (int kt = 0; kt < 3; ++kt)
          xbf[n][kt] = *(const short8*)(xb + ((size_t)(n * 16 + l15) * T_ + t) * KE_ + kqx + kt * 32 + lg * 8);
#pragma unroll
      for (int kt = 0; kt < 3; ++kt)
#pragma unroll
        for (int g = 0; g < 4; ++g) {
          acc[g][0] = __builtin_amdgcn_mfma_f32_16x16x32_bf16(axr[g][kt], xbf[0][kt], acc[g][0], 0, 0, 0);
          acc[g][1] = __builtin_amdgcn_mfma_f32_16x16x32_bf16(axr[g][kt], xbf[1][kt], acc[g][1], 0, 0, 0);
        }
    }
    __builtin_amdgcn_sched_barrier(0);   // keep x-GEMM before the wait/load

    if (s > 0) {
      const int tsrc = dir ? t + 1 : t - 1;
      const size_t toff = (size_t)tsrc * 2048;
      u32x4 q0, q1, q2, q3, q4, q5, q6, q7, q8, q9, qa, qb, qc, qd, qe, qf;
      bool done = false;

      if (__builtin_expect(mirror == 0, 1)) {
        // -- local fast path: sc0 poll on own-XCD L2 (coherent w/ sc0 stores)
        const unsigned short* sp = pbL + toff;
        int ok = 0;
        for (int it = 0; it < 64; ++it) {
          unsigned v;
          asm volatile("global_load_dword %0, %1, off sc0\n\ts_waitcnt vmcnt(0)"
                       : "=v"(v) : "v"(sp) : "memory");
          if (__all(!(v & 0x40004000u))) { ok = 1; break; }
        }
        if (ok) {
          const unsigned short* a0 = rb0 + toff;
          const unsigned short* a1 = rb1 + toff;
          bool bad = true;
          int g2 = 0;
          do {
            BULK16(a0, a1, "sc0");     // same-XCD L2: coherent, retry-safe
            VAL16(bad);
          } while (bad && ++g2 < 50000);
          done = true;
          strikes = 0;
        } else if (++strikes >= 8) {
          mirror = 1;                   // producers not locally visible: latch
        }
      }

      if (__builtin_expect(!done, 0)) {
        // -- MALL mirror path (R10 protocol) ------------------------------
        const unsigned short* sp = pbM + toff;
        unsigned v;
        int guard = 0;
        for (;;) {
          asm volatile("global_load_dword %0, %1, off sc0 sc1\n\ts_waitcnt vmcnt(0)"
                       : "=v"(v) : "v"(sp) : "memory");
          if (__all(!(v & 0x40004000u))) break;
          if (++guard > 50000) break;   // hang safety; never trips co-resident
        }
        const unsigned short* m0 = rm0 + toff;
        const unsigned short* m1 = rm1 + toff;
        bool bad = true;
        int g2 = 0;
        do {
          BULK16(m0, m1, "sc0 sc1");
          VAL16(bad);
        } while (bad && ++g2 < 50000);
      }

      short8 bf0[8], bf1[8];
      bf0[0] = __builtin_bit_cast(short8, q0); bf0[1] = __builtin_bit_cast(short8, q1);
      bf0[2] = __builtin_bit_cast(short8, q2); bf0[3] = __builtin_bit_cast(short8, q3);
      bf0[4] = __builtin_bit_cast(short8, q4); bf0[5] = __builtin_bit_cast(short8, q5);
      bf0[6] = __builtin_bit_cast(short8, q6); bf0[7] = __builtin_bit_cast(short8, q7);
      bf1[0] = __builtin_bit_cast(short8, q8); bf1[1] = __builtin_bit_cast(short8, q9);
      bf1[2] = __builtin_bit_cast(short8, qa); bf1[3] = __builtin_bit_cast(short8, qb);
      bf1[4] = __builtin_bit_cast(short8, qc); bf1[5] = __builtin_bit_cast(short8, qd);
      bf1[6] = __builtin_bit_cast(short8, qe); bf1[7] = __builtin_bit_cast(short8, qf);

#pragma unroll
      for (int ktl = 0; ktl < 8; ++ktl) {
#pragma unroll
        for (int g = 0; g < 4; ++g) {
          acc[g][0] = __builtin_amdgcn_mfma_f32_16x16x32_bf16(afr[g][ktl], bf0[ktl], acc[g][0], 0, 0, 0);
          acc[g][1] = __builtin_amdgcn_mfma_f32_16x16x32_bf16(afr[g][ktl], bf1[ktl], acc[g][1], 0, 0, 0);
        }
      }
    }

    // -- write K-partial sums to LDS (scalar, stride-21: conflict-free) --
#pragma unroll
    for (int g = 0; g < 4; ++g)
#pragma unroll
      for (int n = 0; n < 2; ++n)
#pragma unroll
        for (int j = 0; j < 4; ++j)
          Gp[wid][g][n * 16 + l15][lg * 4 + j] = acc[g][n][j];
    __syncthreads();

    // -- activations: thread handles (u,b) and (u+8,b) -------------------
#pragma unroll
    for (int p = 0; p < 2; ++p) {
      int ul = u + p * 8;
      float gi = Gp[0][0][b][ul] + Gp[1][0][b][ul] + Gp[2][0][b][ul] + Gp[3][0][b][ul] + bsum[p][0];
      float gf = Gp[0][1][b][ul] + Gp[1][1][b][ul] + Gp[2][1][b][ul] + Gp[3][1][b][ul] + bsum[p][1];
      float gg = Gp[0][2][b][ul] + Gp[1][2][b][ul] + Gp[2][2][b][ul] + Gp[3][2][b][ul] + bsum[p][2];
      float go = Gp[0][3][b][ul] + Gp[1][3][b][ul] + Gp[2][3][b][ul] + Gp[3][3][b][ul] + bsum[p][3];
      cst[p] = sigm(gf) * cst[p] + sigm(gi) * tanh_fast(gg);
      float hv = sigm(go) * tanh_fast(cst[p]);
      htmp[b][ul] = f2bu(hv);
    }
    __syncthreads();

    // -- wave 0: dual-publish h (sc0 -> local L2, sc0 sc1 -> MALL mirror) -
    if (tid < 64) {
      int bb = tid >> 1, half = tid & 1;
      u32x4 v = *(const u32x4*)&htmp[bb][half * 8];
      size_t hoff = ((size_t)bb * T_ + t) * 2048 + dir * H_ + w * NU_ + half * 8;
      unsigned short* hpL = outb + hoff;
      unsigned short* hpM = outm + hoff;
      asm volatile("global_store_dwordx4 %0, %1, off sc0" :: "v"(hpL), "v"(v) : "memory");
      asm volatile("global_store_dwordx4 %0, %1, off sc0 sc1" :: "v"(hpM), "v"(v) : "memory");
    }
  }
}

// ---------------------------------------------------------------------------
// K3: th1[row][a] = tanh( out[row][:] . W1b[a][:] )
// ---------------------------------------------------------------------------
__global__ __launch_bounds__(256, 1) void k3_s1(const unsigned short* __restrict__ outb,
                                                const unsigned short* __restrict__ w1b,
                                                unsigned short* __restrict__ th1) {
  const int rb = blockIdx.x;
  const int wid = threadIdx.x >> 6, lane = threadIdx.x & 63;
  const int m = wid & 1, nh = wid >> 1;
  const int l15 = lane & 15, lg = lane >> 4;

  f32x4 acc[12];
#pragma unroll
  for (int nt = 0; nt < 12; ++nt) acc[nt] = (f32x4){0.f, 0.f, 0.f, 0.f};

  const unsigned short* arow = outb + ((size_t)rb * 32 + m * 16 + l15) * 2048;
  for (int kt = 0; kt < 64; ++kt) {
    short8 af = *(const short8*)(arow + kt * 32 + lg * 8);
#pragma unroll
    for (int nt = 0; nt < 12; ++nt) {
      int col = nh * 192 + nt * 16 + l15;
      short8 bf = *(const short8*)(w1b + (size_t)col * 2048 + kt * 32 + lg * 8);
      acc[nt] = __builtin_amdgcn_mfma_f32_16x16x32_bf16(af, bf, acc[nt], 0, 0, 0);
    }
  }
#pragma unroll
  for (int nt = 0; nt < 12; ++nt) {
#pragma unroll
    for (int j = 0; j < 4; ++j) {
      int row = rb * 32 + m * 16 + lg * 4 + j;
      int col = nh * 192 + nt * 16 + l15;
      th1[(size_t)row * AC_ + col] = f2bu(tanh_fast(acc[nt][j]));
    }
  }
}

// ---------------------------------------------------------------------------
// K4: abuf[b][r][t] = th1[row][:350] . W2[r][:350]
// ---------------------------------------------------------------------------
__global__ void k4_s2(const unsigned short* __restrict__ th1, const float* __restrict__ W2,
                      float* __restrict__ abuf) {
  int idx = blockIdx.x * 256 + threadIdx.x;
  int row = idx >> 5, r = idx & 31;
  if (r >= R_) return;
  const unsigned short* tp = th1 + (size_t)row * AC_;
  const float* wp = W2 + r * AD_;
  float acc = 0.f;
  for (int a = 0; a < AD_; ++a) acc = fmaf(b2f(tp[a]), wp[a], acc);
  int b = row >> 9, t = row & 511;
  abuf[((size_t)b * R_ + r) * T_ + t] = acc;
}

// ---------------------------------------------------------------------------
// K5: masked softmax over t (in place).  One wave per (b,r).
// ---------------------------------------------------------------------------
__global__ void k5_sm(float* __restrict__ abuf, const int* __restrict__ lens) {
  int wv = blockIdx.x * 4 + (threadIdx.x >> 6);
  int lane = threadIdx.x & 63;
  if (wv >= B_ * R_) return;
  int b = wv / R_, r = wv % R_;
  int len = lens[b];
  float* row = abuf + ((size_t)b * R_ + r) * T_;
  float v[8];
  float mx = -1e30f;
#pragma unroll
  for (int i = 0; i < 8; ++i) {
    int t = lane + i * 64;
    float x = (t < len) ? row[t] : -1e30f;
    v[i] = x;
    mx = fmaxf(mx, x);
  }
#pragma unroll
  for (int o = 32; o > 0; o >>= 1) mx = fmaxf(mx, __shfl_xor(mx, o));
  float sum = 0.f;
#pragma unroll
  for (int i = 0; i < 8; ++i) {
    float e = (v[i] > -1e29f) ? __expf(v[i] - mx) : 0.f;
    v[i] = e;
    sum += e;
  }
#pragma unroll
  for (int o = 32; o > 0; o >>= 1) sum += __shfl_xor(sum, o);
  float inv = 1.f / sum;
#pragma unroll
  for (int i = 0; i < 8; ++i) row[lane + i * 64] = v[i] * inv;
}

// ---------------------------------------------------------------------------
// K6: M[b][r][h] = sum_t A[b][r][t] * out[b][t][h].  Writes mbuf as bf16.
// ---------------------------------------------------------------------------
__global__ __launch_bounds__(256) void k6_m(const float* __restrict__ abuf,
                                            const unsigned short* __restrict__ outb,
                                            unsigned short* __restrict__ mbuf) {
  int b = blockIdx.x >> 4, hb = blockIdx.x & 15;
  __shared__ float As[R_ * T_];
  for (int i = threadIdx.x; i < R_ * T_; i += 256) As[i] = abuf[(size_t)b * R_ * T_ + i];
  __syncthreads();
  int h = threadIdx.x & 127, rh = threadIdx.x >> 7;
  float acc[15];
#pragma unroll
  for (int rr = 0; rr < 15; ++rr) acc[rr] = 0.f;
  const unsigned short* op = outb + (size_t)b * T_ * 2048 + hb * 128 + h;
  for (int t = 0; t < T_; ++t) {
    float vv = b2f(op[(size_t)t * 2048]);
#pragma unroll
    for (int rr = 0; rr < 15; ++rr) acc[rr] = fmaf(As[(rh * 15 + rr) * T_ + t], vv, acc[rr]);
  }
#pragma unroll
  for (int rr = 0; rr < 15; ++rr)
    mbuf[(size_t)b * FEAT_ + (size_t)(rh * 15 + rr) * 2048 + hb * 128 + h] = f2bu(acc[rr]);
}

// ---------------------------------------------------------------------------
// K7: per-sample penalty partial: ||A A^T - I||_F^2.
// ---------------------------------------------------------------------------
__global__ __launch_bounds__(256) void k7_pen(const float* __restrict__ abuf,
                                              float* __restrict__ penp) {
  int b = blockIdx.x;
  __shared__ float As[R_ * 515];
  __shared__ float red[256];
  for (int i = threadIdx.x; i < R_ * T_; i += 256) {
    int r = i >> 9, t = i & 511;
    As[r * 515 + t] = abuf[(size_t)b * R_ * T_ + i];
  }
  __syncthreads();
  float psum = 0.f;
  for (int p = threadIdx.x; p < R_ * R_; p += 256) {
    int r = p / R_, s = p % R_;
    const float* pr = As + r * 515;
    const float* ps = As + s * 515;
    float d = 0.f;
    for (int t = 0; t < T_; ++t) d = fmaf(pr[t], ps[t], d);
    d -= (r == s) ? 1.f : 0.f;
    psum += d * d;
  }
  red[threadIdx.x] = psum;
  __syncthreads();
  for (int o = 128; o > 0; o >>= 1) {
    if (threadIdx.x < o) red[threadIdx.x] += red[threadIdx.x + o];
    __syncthreads();
  }
  if (threadIdx.x == 0) penp[b] = red[0];
}

// ---------------------------------------------------------------------------
// K8 v2: hidsum[b][m] += wmlpb[m-tile][k-tile] . mbuf[b][k-tile]  (MFMA)
// ---------------------------------------------------------------------------
__global__ __launch_bounds__(256, 1) void k8_mlp(const unsigned short* __restrict__ wmlpb,
                                                 const unsigned short* __restrict__ mbuf,
                                                 float* __restrict__ hid) {
  const int mblk = blockIdx.x >> 4, kblk = blockIdx.x & 15;
  const int wid = threadIdx.x >> 6, lane = threadIdx.x & 63;
  const int l15 = lane & 15, lg = lane >> 4;
  const int kq = kblk * 3840 + wid * 960;

  f32x4 acc[2][2];
#pragma unroll
  for (int i = 0; i < 2; ++i)
#pragma unroll
    for (int j = 0; j < 2; ++j) acc[i][j] = (f32x4){0.f, 0.f, 0.f, 0.f};

  const unsigned short* ap0 = wmlpb + (size_t)(mblk * 32 + l15) * FEAT_ + kq + lg * 8;
  const unsigned short* ap1 = ap0 + (size_t)16 * FEAT_;
  const unsigned short* bp0 = mbuf + (size_t)l15 * FEAT_ + kq + lg * 8;
  const unsigned short* bp1 = bp0 + (size_t)16 * FEAT_;
  for (int kt = 0; kt < 30; ++kt) {
    short8 a0 = *(const short8*)(ap0 + kt * 32);
    short8 a1 = *(const short8*)(ap1 + kt * 32);
    short8 b0 = *(const short8*)(bp0 + kt * 32);
    short8 b1 = *(const short8*)(bp1 + kt * 32);
    acc[0][0] = __builtin_amdgcn_mfma_f32_16x16x32_bf16(a0, b0, acc[0][0], 0, 0, 0);
    acc[0][1] = __builtin_amdgcn_mfma_f32_16x16x32_bf16(a0, b1, acc[0][1], 0, 0, 0);
    acc[1][0] = __builtin_amdgcn_mfma_f32_16x16x32_bf16(a1, b0, acc[1][0], 0, 0, 0);
    acc[1][1] = __builtin_amdgcn_mfma_f32_16x16x32_bf16(a1, b1, acc[1][1], 0, 0, 0);
  }

  __shared__ float red[4][32][33];
#pragma unroll
  for (int mi = 0; mi < 2; ++mi)
#pragma unroll
    for (int ni = 0; ni < 2; ++ni)
#pragma unroll
      for (int j = 0; j < 4; ++j)
        red[wid][mi * 16 + lg * 4 + j][ni * 16 + l15] = acc[mi][ni][j];
  __syncthreads();

  int m = threadIdx.x >> 3, b4 = (threadIdx.x & 7) * 4;
#pragma unroll
  for (int k = 0; k < 4; ++k) {
    int bb = b4 + k;
    float s = red[0][m][bb] + red[1][m][bb] + red[2][m][bb] + red[3][m][bb];
    atomicAdd(&hid[(size_t)bb * MH_ + mblk * 32 + m], s);
  }
}

// ---------------------------------------------------------------------------
// K9: decoded = softmax( relu(hid+b_mlp) @ W_dec^T + b_dec ); penal = mean.
// ---------------------------------------------------------------------------
__global__ void k9_out(const float* __restrict__ hid, const float* __restrict__ b_mlp,
                       const float* __restrict__ W_dec, const float* __restrict__ b_dec,
                       const float* __restrict__ penp, float* __restrict__ out) {
  int tid = threadIdx.x;
  if (tid < 64) {
    int b = tid >> 1, c = tid & 1;
    const float* hp = hid + (size_t)b * MH_;
    const float* wp = W_dec + (size_t)c * MH_;
    float acc = b_dec[c];
    for (int k = 0; k < MH_; ++k) {
      float hk = fmaxf(hp[k] + b_mlp[k], 0.f);
      acc = fmaf(hk, wp[k], acc);
    }
    float other = __shfl_xor(acc, 1);
    float mx = fmaxf(acc, other);
    float e = __expf(acc - mx), eo = __expf(other - mx);
    out[b * 2 + c] = e / (e + eo);
  } else if (tid == 64) {
    float s = 0.f;
    for (int b = 0; b < B_; ++b) s += penp[b];
    out[64] = s * (1.f / 32.f);
  }
}

// ---------------------------------------------------------------------------
extern "C" void kernel_launch(void* const* d_in, const int* in_sizes, int n_in,
                              void* d_out, int out_size, void* d_ws, size_t ws_size,
                              hipStream_t stream) {
  const int* inp = (const int*)d_in[0];
  const int* lens = (const int*)d_in[1];
  const float* W_emb = (const float*)d_in[2];
  const float* W_ih = (const float*)d_in[3];
  const float* W_hh = (const float*)d_in[4];
  const float* b_ih = (const float*)d_in[5];
  const float* b_hh = (const float*)d_in[6];
  const float* W1 = (const float*)d_in[7];
  const float* W2 = (const float*)d_in[8];
  const float* W_mlp = (const float*)d_in[9];
  const float* b_mlp = (const float*)d_in[10];
  const float* W_dec = (const float*)d_in[11];
  const float* b_dec = (const float*)d_in[12];
  float* out = (float*)d_out;

  char* ws = (char*)d_ws;
  size_t off = 0;
  auto take = [&](size_t bytes) -> char* {
    char* p = ws + off;
    off = (off + bytes + 255) & ~(size_t)255;
    return p;
  };
  unsigned short* outb = (unsigned short*)take((size_t)B_ * T_ * 2048 * 2);     // 67.1 MB
  unsigned short* outm = (unsigned short*)take((size_t)B_ * T_ * 2048 * 2);     // 67.1 MB (mirror)
  unsigned short* xb = (unsigned short*)take((size_t)16384 * KE_ * 2);          // 12.6 MB
  unsigned short* wihb = (unsigned short*)take((size_t)8192 * KE_ * 2);         // 6.3 MB
  unsigned short* w1b = (unsigned short*)take((size_t)AC_ * 2048 * 2);          // 1.6 MB
  unsigned short* wmlpb = (unsigned short*)take((size_t)MH_ * FEAT_ * 2);       // 62.9 MB
  unsigned short* th1 = (unsigned short*)take((size_t)16384 * AC_ * 2);         // 12.6 MB
  float* abuf = (float*)take((size_t)B_ * R_ * T_ * 4);                         // 2.0 MB
  unsigned short* mbuf = (unsigned short*)take((size_t)B_ * FEAT_ * 2);         // 3.9 MB
  float* penp = (float*)take(B_ * 4);
  float* hid = (float*)take((size_t)B_ * MH_ * 4);
  int* pool = (int*)take(8 * 4);

  if (off > ws_size) {  // unambiguous failure signal: NaN output
    hipMemsetAsync(d_out, 0xFF, (size_t)out_size * 4, stream);
    return;
  }

  // sentinel-init both h buffers: 0xFFFF bf16 has bit14 set => "unwritten"
  hipMemsetAsync(outb, 0xFF, (size_t)B_ * T_ * 2048 * 2, stream);
  hipMemsetAsync(outm, 0xFF, (size_t)B_ * T_ * 2048 * 2, stream);
  hipMemsetAsync(hid, 0, (size_t)B_ * MH_ * 4, stream);
  hipMemsetAsync(pool, 0, 8 * 4, stream);

  k0_prep<<<2048, 256, 0, stream>>>(inp, W_emb, W_ih, W1, W_mlp, xb, wihb, w1b, wmlpb);
  k2_rnn<<<2048, 256, 0, stream>>>(W_hh, wihb, xb, b_ih, b_hh, outb, outm, pool);
  k3_s1<<<512, 256, 0, stream>>>(outb, w1b, th1);
  k4_s2<<<2048, 256, 0, stream>>>(th1, W2, abuf);
  k5_sm<<<240, 256, 0, stream>>>(abuf, lens);
  k6_m<<<512, 256, 0, stream>>>(abuf, outb, mbuf);
  k7_pen<<<32, 256, 0, stream>>>(abuf, penp);
  k8_mlp<<<256, 256, 0, stream>>>(wmlpb, mbuf, hid);
  k9_out<<<1, 128, 0, stream>>>(hid, b_mlp, W_dec, b_dec, penp, out);
}

// Round 12
// 2263.478 us; speedup vs baseline: 1.8530x; 1.8530x over previous
//
#include <hip/hip_runtime.h>
#include <stdint.h>

typedef __attribute__((ext_vector_type(8))) short short8;
typedef __attribute__((ext_vector_type(4))) float f32x4;
typedef __attribute__((ext_vector_type(4))) unsigned int u32x4;

#define B_    32
#define T_    512
#define E_    300
#define KE_   384     // padded embed K (multiple of 128 for 4-wave x 32 split)
#define H_    1024
#define G4_   4096
#define R_    30
#define AD_   350
#define AC_   384
#define MH_   512
#define FEAT_ 61440
#define NWG_  64      // workgroups per direction
#define NU_   16      // hidden units per workgroup
#define DTICK 27ull   // pacing delta: ~1.08us @ 25MHz RTC (s_memrealtime)

__device__ __forceinline__ unsigned short f2bu(float f) {
  unsigned int x = __builtin_bit_cast(unsigned int, f);
  x += 0x7fffu + ((x >> 16) & 1u);
  return (unsigned short)(x >> 16);
}
__device__ __forceinline__ float b2f(unsigned short u) {
  return __builtin_bit_cast(float, (unsigned int)u << 16);
}
__device__ __forceinline__ float sigm(float x) {
  return __builtin_amdgcn_rcpf(1.f + __expf(-x));
}
__device__ __forceinline__ float tanh_fast(float x) {
  return 1.f - 2.f * __builtin_amdgcn_rcpf(1.f + __expf(2.f * x));
}

// Gathered 16x dwordx4 load of the wave's B-fragments from hpub.
// 4 base pointers (chunk pairs), imm offsets 0/2048 (ktl) and +512 (row+16).
#define BULK16G(b0p, b1p, b2p, b3p, FL)                                         \
  asm volatile(                                                                 \
      "global_load_dwordx4 %0, %16, off " FL "\n\t"                             \
      "global_load_dwordx4 %1, %16, off offset:2048 " FL "\n\t"                 \
      "global_load_dwordx4 %2, %17, off " FL "\n\t"                             \
      "global_load_dwordx4 %3, %17, off offset:2048 " FL "\n\t"                 \
      "global_load_dwordx4 %4, %18, off " FL "\n\t"                             \
      "global_load_dwordx4 %5, %18, off offset:2048 " FL "\n\t"                 \
      "global_load_dwordx4 %6, %19, off " FL "\n\t"                             \
      "global_load_dwordx4 %7, %19, off offset:2048 " FL "\n\t"                 \
      "global_load_dwordx4 %8, %16, off offset:512 " FL "\n\t"                  \
      "global_load_dwordx4 %9, %16, off offset:2560 " FL "\n\t"                 \
      "global_load_dwordx4 %10, %17, off offset:512 " FL "\n\t"                 \
      "global_load_dwordx4 %11, %17, off offset:2560 " FL "\n\t"                \
      "global_load_dwordx4 %12, %18, off offset:512 " FL "\n\t"                 \
      "global_load_dwordx4 %13, %18, off offset:2560 " FL "\n\t"                \
      "global_load_dwordx4 %14, %19, off offset:512 " FL "\n\t"                 \
      "global_load_dwordx4 %15, %19, off offset:2560 " FL "\n\t"                \
      "s_waitcnt vmcnt(0)"                                                      \
      : "=&v"(q0), "=&v"(q1), "=&v"(q2), "=&v"(q3), "=&v"(q4), "=&v"(q5),       \
        "=&v"(q6), "=&v"(q7), "=&v"(q8), "=&v"(q9), "=&v"(qa), "=&v"(qb),       \
        "=&v"(qc), "=&v"(qd), "=&v"(qe), "=&v"(qf)                              \
      : "v"(b0p), "v"(b1p), "v"(b2p), "v"(b3p)                                  \
      : "memory")

// validate: any bf16 half with bit14 set => sentinel/unwritten
#define VAL16(BAD)                                                              \
  {                                                                             \
    u32x4 o01 = q0 | q1, o23 = q2 | q3, o45 = q4 | q5, o67 = q6 | q7;           \
    u32x4 o89 = q8 | q9, oab = qa | qb, ocd = qc | qd, oef = qe | qf;           \
    u32x4 ov4 = ((o01 | o23) | (o45 | o67)) | ((o89 | oab) | (ocd | oef));      \
    unsigned ovv = (ov4[0] | ov4[1]) | (ov4[2] | ov4[3]);                       \
    BAD = (ovv & 0x40004000u) != 0;                                             \
  }

// ---------------------------------------------------------------------------
// K0: cast/pad to bf16: xb[16384][384], wihb[8192][384], w1b[384][2048],
//     wmlpb[512][61440]
// ---------------------------------------------------------------------------
__global__ void k0_prep(const int* __restrict__ inp, const float* __restrict__ W_emb,
                        const float* __restrict__ W_ih, const float* __restrict__ W1,
                        const float* __restrict__ W_mlp,
                        unsigned short* __restrict__ xb, unsigned short* __restrict__ wihb,
                        unsigned short* __restrict__ w1b, unsigned short* __restrict__ wmlpb) {
  const int N1 = 16384 * KE_;
  const int N2 = 8192 * KE_;
  const int N3 = AC_ * 2048;
  const int N4 = MH_ * FEAT_;
  const int NT = N1 + N2 + N3 + N4;
  for (int i = blockIdx.x * blockDim.x + threadIdx.x; i < NT; i += gridDim.x * blockDim.x) {
    if (i < N1) {
      int row = i / KE_, e = i - row * KE_;
      float v = (e < E_) ? W_emb[(size_t)inp[row] * E_ + e] : 0.f;
      xb[i] = f2bu(v);
    } else if (i < N1 + N2) {
      int j = i - N1;
      int rw = j / KE_, e = j - rw * KE_;
      float v = (e < E_) ? W_ih[(size_t)rw * E_ + e] : 0.f;
      wihb[j] = f2bu(v);
    } else if (i < N1 + N2 + N3) {
      int j = i - N1 - N2;
      int a = j >> 11, k = j & 2047;
      float v = (a < AD_) ? W1[(size_t)a * 2048 + k] : 0.f;
      w1b[j] = f2bu(v);
    } else {
      int j = i - N1 - N2 - N3;
      wmlpb[j] = f2bu(W_mlp[j]);
    }
  }
}

// ---------------------------------------------------------------------------
// K2 v12: R10's MALL protocol + producer-contiguous rendezvous buffer.
//   hpub[dir][t][w][b][u]: each producer WG publishes ONE contiguous 1KB
//   burst (8 full cache lines, single writer per line) -> no partial-line
//   merge serialization, no cross-producer false sharing.
//   Consumers gather B-fragments from hpub (coalesced within 2KB windows).
//   outb ([b][t][2048], for k3/k6) is written with plain cached stores off
//   the critical path; dispatch boundary publishes it to later kernels.
// ---------------------------------------------------------------------------
__global__ __launch_bounds__(256, 1) void k2_rnn(const float* __restrict__ Whh,
                                                 const unsigned short* __restrict__ wihb,
                                                 const unsigned short* __restrict__ xb,
                                                 const float* __restrict__ b_ih,
                                                 const float* __restrict__ b_hh,
                                                 unsigned short* __restrict__ outb,
                                                 unsigned short* __restrict__ hpub) {
  const int dir = blockIdx.x >> 6;
  const int w = blockIdx.x & 63;
  const int tid = threadIdx.x;
  const int wid = tid >> 6, lane = tid & 63;
  const int l15 = lane & 15, lg = lane >> 4;

  __shared__ float Gp[4][4][32][21];               // [wave][gate][batch][unit+pad21]
  __shared__ __align__(16) unsigned short htmp[32][16];

  // ---- preload W_hh K-quarter as bf16 A-frags --------------------------
  short8 afr[4][8];
  {
    const int kq = wid << 8;
#pragma unroll
    for (int g = 0; g < 4; ++g) {
      const float* wp = Whh + ((size_t)dir * G4_ + g * H_ + w * NU_ + l15) * H_ + kq + lg * 8;
#pragma unroll
      for (int ktl = 0; ktl < 8; ++ktl) {
        float4 f0 = *(const float4*)(wp + ktl * 32);
        float4 f1 = *(const float4*)(wp + ktl * 32 + 4);
        short8 s;
        s[0] = (short)f2bu(f0.x); s[1] = (short)f2bu(f0.y);
        s[2] = (short)f2bu(f0.z); s[3] = (short)f2bu(f0.w);
        s[4] = (short)f2bu(f1.x); s[5] = (short)f2bu(f1.y);
        s[6] = (short)f2bu(f1.z); s[7] = (short)f2bu(f1.w);
        afr[g][ktl] = s;
      }
    }
  }

  // ---- preload W_ih K-slice (96 of 384) as bf16 A-frags ----------------
  const int kqx = wid * 96;
  short8 axr[4][3];
#pragma unroll
  for (int g = 0; g < 4; ++g) {
    const unsigned short* xp = wihb + ((size_t)dir * G4_ + g * H_ + w * NU_ + l15) * KE_ + kqx + lg * 8;
#pragma unroll
    for (int kt = 0; kt < 3; ++kt) axr[g][kt] = *(const short8*)(xp + kt * 32);
  }

  const int u = tid >> 5;    // activation role: unit pair (u, u+8)
  const int b = tid & 31;    // activation role: batch

  float bsum[2][4];
#pragma unroll
  for (int p = 0; p < 2; ++p)
#pragma unroll
    for (int g = 0; g < 4; ++g) {
      int row = dir * G4_ + g * H_ + w * NU_ + u + p * 8;
      bsum[p][g] = b_ih[row] + b_hh[row];
    }

  // hpub gather base (per wave/lane): chunk = (dir,t,w) of 512 ushorts.
  // wave region = 16 chunks [wid*16, wid*16+16); lane picks chunk via
  // (lg>>1) and imm-offsets; within-chunk = b*16 + (lg&1)*8.
  const size_t hlane = (size_t)wid * 8192 + (size_t)(lg >> 1) * 512 + l15 * 16 + (lg & 1) * 8;
  // thin-poll base: lane i -> producer i's chunk word 0
  const size_t hpoll = (size_t)lane * 512;

  float cst[2] = {0.f, 0.f};
  unsigned long long pprev = __builtin_amdgcn_s_memrealtime();

#pragma unroll 1
  for (int s = 0; s < T_; ++s) {
    const int t = dir ? (T_ - 1 - s) : s;

    f32x4 acc[4][2];
#pragma unroll
    for (int g = 0; g < 4; ++g) {
      acc[g][0] = (f32x4){0.f, 0.f, 0.f, 0.f};
      acc[g][1] = (f32x4){0.f, 0.f, 0.f, 0.f};
    }

    // -- x-GEMM: independent of h; overlaps the pacing window ------------
    {
      short8 xbf[2][3];
#pragma unroll
      for (int n = 0; n < 2; ++n)
#pragma unroll
        for (int kt = 0; kt < 3; ++kt)
          xbf[n][kt] = *(const short8*)(xb + ((size_t)(n * 16 + l15) * T_ + t) * KE_ + kqx + kt * 32 + lg * 8);
#pragma unroll
      for (int kt = 0; kt < 3; ++kt)
#pragma unroll
        for (int g = 0; g < 4; ++g) {
          acc[g][0] = __builtin_amdgcn_mfma_f32_16x16x32_bf16(axr[g][kt], xbf[0][kt], acc[g][0], 0, 0, 0);
          acc[g][1] = __builtin_amdgcn_mfma_f32_16x16x32_bf16(axr[g][kt], xbf[1][kt], acc[g][1], 0, 0, 0);
        }
    }
    __builtin_amdgcn_sched_barrier(0);   // keep x-GEMM before the wait/load

    if (s > 0) {
      const int tsrc = dir ? t + 1 : t - 1;
      const unsigned short* hbase = hpub + (size_t)(dir * T_ + tsrc) * 32768;
      const unsigned short* B0 = hbase + hlane;
      const unsigned short* B1 = B0 + 2048;     // +4096 bytes
      const unsigned short* B2 = B0 + 4096;
      const unsigned short* B3 = B0 + 6144;
      u32x4 q0, q1, q2, q3, q4, q5, q6, q7, q8, q9, qa, qb, qc, qd, qe, qf;

      // -- pace: spin on scalar clock until own prev publish + DTICK ------
      {
        unsigned long long tgt = pprev + DTICK;
        unsigned long long now;
        do { now = __builtin_amdgcn_s_memrealtime(); } while (now < tgt);
      }

      // -- speculative payload: ONE cached (sc0) gather, validate ---------
      BULK16G(B0, B1, B2, B3, "sc0");
      bool bad; VAL16(bad);
      if (__builtin_expect(bad, 0)) {
        // backstop: thin-poll the 64 producers, then gather-retry (MALL)
        const unsigned short* sp = hbase + hpoll;
        unsigned v;
        int guard = 0;
        for (;;) {
          asm volatile("global_load_dword %0, %1, off sc0 sc1\n\ts_waitcnt vmcnt(0)"
                       : "=v"(v) : "v"(sp) : "memory");
          if (__all(!(v & 0x40004000u))) break;
          if (++guard > 50000) break;   // hang safety; never trips co-resident
        }
        int g2 = 0;
        do {
          BULK16G(B0, B1, B2, B3, "sc0 sc1");
          VAL16(bad);
        } while (bad && ++g2 < 50000);
      }

      short8 bf0[8], bf1[8];
      bf0[0] = __builtin_bit_cast(short8, q0); bf0[1] = __builtin_bit_cast(short8, q1);
      bf0[2] = __builtin_bit_cast(short8, q2); bf0[3] = __builtin_bit_cast(short8, q3);
      bf0[4] = __builtin_bit_cast(short8, q4); bf0[5] = __builtin_bit_cast(short8, q5);
      bf0[6] = __builtin_bit_cast(short8, q6); bf0[7] = __builtin_bit_cast(short8, q7);
      bf1[0] = __builtin_bit_cast(short8, q8); bf1[1] = __builtin_bit_cast(short8, q9);
      bf1[2] = __builtin_bit_cast(short8, qa); bf1[3] = __builtin_bit_cast(short8, qb);
      bf1[4] = __builtin_bit_cast(short8, qc); bf1[5] = __builtin_bit_cast(short8, qd);
      bf1[6] = __builtin_bit_cast(short8, qe); bf1[7] = __builtin_bit_cast(short8, qf);

#pragma unroll
      for (int ktl = 0; ktl < 8; ++ktl) {
#pragma unroll
        for (int g = 0; g < 4; ++g) {
          acc[g][0] = __builtin_amdgcn_mfma_f32_16x16x32_bf16(afr[g][ktl], bf0[ktl], acc[g][0], 0, 0, 0);
          acc[g][1] = __builtin_amdgcn_mfma_f32_16x16x32_bf16(afr[g][ktl], bf1[ktl], acc[g][1], 0, 0, 0);
        }
      }
    }

    // -- write K-partial sums to LDS (scalar, stride-21: conflict-free) --
#pragma unroll
    for (int g = 0; g < 4; ++g)
#pragma unroll
      for (int n = 0; n < 2; ++n)
#pragma unroll
        for (int j = 0; j < 4; ++j)
          Gp[wid][g][n * 16 + l15][lg * 4 + j] = acc[g][n][j];
    __syncthreads();

    // -- activations: thread handles (u,b) and (u+8,b) -------------------
#pragma unroll
    for (int p = 0; p < 2; ++p) {
      int ul = u + p * 8;
      float gi = Gp[0][0][b][ul] + Gp[1][0][b][ul] + Gp[2][0][b][ul] + Gp[3][0][b][ul] + bsum[p][0];
      float gf = Gp[0][1][b][ul] + Gp[1][1][b][ul] + Gp[2][1][b][ul] + Gp[3][1][b][ul] + bsum[p][1];
      float gg = Gp[0][2][b][ul] + Gp[1][2][b][ul] + Gp[2][2][b][ul] + Gp[3][2][b][ul] + bsum[p][2];
      float go = Gp[0][3][b][ul] + Gp[1][3][b][ul] + Gp[2][3][b][ul] + Gp[3][3][b][ul] + bsum[p][3];
      cst[p] = sigm(gf) * cst[p] + sigm(gi) * tanh_fast(gg);
      float hv = sigm(go) * tanh_fast(cst[p]);
      htmp[b][ul] = f2bu(hv);
    }
    __syncthreads();

    // -- record anchor; wave 0 publishes: hpub (contiguous 1KB, sc0 sc1)
    //    gates the rendezvous; outb (plain cached) feeds k3/k6 later. -----
    pprev = __builtin_amdgcn_s_memrealtime();
    if (tid < 64) {
      int bb = tid >> 1, half = tid & 1;
      u32x4 v = *(const u32x4*)&htmp[bb][half * 8];
      unsigned short* hp = hpub + (size_t)(dir * T_ + t) * 32768 + (size_t)w * 512 + bb * 16 + half * 8;
      asm volatile("global_store_dwordx4 %0, %1, off sc0 sc1" :: "v"(hp), "v"(v) : "memory");
      *(u32x4*)(outb + ((size_t)bb * T_ + t) * 2048 + dir * H_ + w * NU_ + half * 8) = v;
    }
  }
}

// ---------------------------------------------------------------------------
// K3: th1[row][a] = tanh( out[row][:] . W1b[a][:] )
// ---------------------------------------------------------------------------
__global__ __launch_bounds__(256, 1) void k3_s1(const unsigned short* __restrict__ outb,
                                                const unsigned short* __restrict__ w1b,
                                                unsigned short* __restrict__ th1) {
  const int rb = blockIdx.x;
  const int wid = threadIdx.x >> 6, lane = threadIdx.x & 63;
  const int m = wid & 1, nh = wid >> 1;
  const int l15 = lane & 15, lg = lane >> 4;

  f32x4 acc[12];
#pragma unroll
  for (int nt = 0; nt < 12; ++nt) acc[nt] = (f32x4){0.f, 0.f, 0.f, 0.f};

  const unsigned short* arow = outb + ((size_t)rb * 32 + m * 16 + l15) * 2048;
  for (int kt = 0; kt < 64; ++kt) {
    short8 af = *(const short8*)(arow + kt * 32 + lg * 8);
#pragma unroll
    for (int nt = 0; nt < 12; ++nt) {
      int col = nh * 192 + nt * 16 + l15;
      short8 bf = *(const short8*)(w1b + (size_t)col * 2048 + kt * 32 + lg * 8);
      acc[nt] = __builtin_amdgcn_mfma_f32_16x16x32_bf16(af, bf, acc[nt], 0, 0, 0);
    }
  }
#pragma unroll
  for (int nt = 0; nt < 12; ++nt) {
#pragma unroll
    for (int j = 0; j < 4; ++j) {
      int row = rb * 32 + m * 16 + lg * 4 + j;
      int col = nh * 192 + nt * 16 + l15;
      th1[(size_t)row * AC_ + col] = f2bu(tanh_fast(acc[nt][j]));
    }
  }
}

// ---------------------------------------------------------------------------
// K4: abuf[b][r][t] = th1[row][:350] . W2[r][:350]
// ---------------------------------------------------------------------------
__global__ void k4_s2(const unsigned short* __restrict__ th1, const float* __restrict__ W2,
                      float* __restrict__ abuf) {
  int idx = blockIdx.x * 256 + threadIdx.x;
  int row = idx >> 5, r = idx & 31;
  if (r >= R_) return;
  const unsigned short* tp = th1 + (size_t)row * AC_;
  const float* wp = W2 + r * AD_;
  float acc = 0.f;
  for (int a = 0; a < AD_; ++a) acc = fmaf(b2f(tp[a]), wp[a], acc);
  int b = row >> 9, t = row & 511;
  abuf[((size_t)b * R_ + r) * T_ + t] = acc;
}

// ---------------------------------------------------------------------------
// K5: masked softmax over t (in place).  One wave per (b,r).
// ---------------------------------------------------------------------------
__global__ void k5_sm(float* __restrict__ abuf, const int* __restrict__ lens) {
  int wv = blockIdx.x * 4 + (threadIdx.x >> 6);
  int lane = threadIdx.x & 63;
  if (wv >= B_ * R_) return;
  int b = wv / R_, r = wv % R_;
  int len = lens[b];
  float* row = abuf + ((size_t)b * R_ + r) * T_;
  float v[8];
  float mx = -1e30f;
#pragma unroll
  for (int i = 0; i < 8; ++i) {
    int t = lane + i * 64;
    float x = (t < len) ? row[t] : -1e30f;
    v[i] = x;
    mx = fmaxf(mx, x);
  }
#pragma unroll
  for (int o = 32; o > 0; o >>= 1) mx = fmaxf(mx, __shfl_xor(mx, o));
  float sum = 0.f;
#pragma unroll
  for (int i = 0; i < 8; ++i) {
    float e = (v[i] > -1e29f) ? __expf(v[i] - mx) : 0.f;
    v[i] = e;
    sum += e;
  }
#pragma unroll
  for (int o = 32; o > 0; o >>= 1) sum += __shfl_xor(sum, o);
  float inv = 1.f / sum;
#pragma unroll
  for (int i = 0; i < 8; ++i) row[lane + i * 64] = v[i] * inv;
}

// ---------------------------------------------------------------------------
// K6: M[b][r][h] = sum_t A[b][r][t] * out[b][t][h].  Writes mbuf as bf16.
// ---------------------------------------------------------------------------
__global__ __launch_bounds__(256) void k6_m(const float* __restrict__ abuf,
                                            const unsigned short* __restrict__ outb,
                                            unsigned short* __restrict__ mbuf) {
  int b = blockIdx.x >> 4, hb = blockIdx.x & 15;
  __shared__ float As[R_ * T_];
  for (int i = threadIdx.x; i < R_ * T_; i += 256) As[i] = abuf[(size_t)b * R_ * T_ + i];
  __syncthreads();
  int h = threadIdx.x & 127, rh = threadIdx.x >> 7;
  float acc[15];
#pragma unroll
  for (int rr = 0; rr < 15; ++rr) acc[rr] = 0.f;
  const unsigned short* op = outb + (size_t)b * T_ * 2048 + hb * 128 + h;
  for (int t = 0; t < T_; ++t) {
    float vv = b2f(op[(size_t)t * 2048]);
#pragma unroll
    for (int rr = 0; rr < 15; ++rr) acc[rr] = fmaf(As[(rh * 15 + rr) * T_ + t], vv, acc[rr]);
  }
#pragma unroll
  for (int rr = 0; rr < 15; ++rr)
    mbuf[(size_t)b * FEAT_ + (size_t)(rh * 15 + rr) * 2048 + hb * 128 + h] = f2bu(acc[rr]);
}

// ---------------------------------------------------------------------------
// K7: per-sample penalty partial: ||A A^T - I||_F^2.
// ---------------------------------------------------------------------------
__global__ __launch_bounds__(256) void k7_pen(const float* __restrict__ abuf,
                                              float* __restrict__ penp) {
  int b = blockIdx.x;
  __shared__ float As[R_ * 515];
  __shared__ float red[256];
  for (int i = threadIdx.x; i < R_ * T_; i += 256) {
    int r = i >> 9, t = i & 511;
    As[r * 515 + t] = abuf[(size_t)b * R_ * T_ + i];
  }
  __syncthreads();
  float psum = 0.f;
  for (int p = threadIdx.x; p < R_ * R_; p += 256) {
    int r = p / R_, s = p % R_;
    const float* pr = As + r * 515;
    const float* ps = As + s * 515;
    float d = 0.f;
    for (int t = 0; t < T_; ++t) d = fmaf(pr[t], ps[t], d);
    d -= (r == s) ? 1.f : 0.f;
    psum += d * d;
  }
  red[threadIdx.x] = psum;
  __syncthreads();
  for (int o = 128; o > 0; o >>= 1) {
    if (threadIdx.x < o) red[threadIdx.x] += red[threadIdx.x + o];
    __syncthreads();
  }
  if (threadIdx.x == 0) penp[b] = red[0];
}

// ---------------------------------------------------------------------------
// K8 v2: hidsum[b][m] += wmlpb[m-tile][k-tile] . mbuf[b][k-tile]  (MFMA)
// ---------------------------------------------------------------------------
__global__ __launch_bounds__(256, 1) void k8_mlp(const unsigned short* __restrict__ wmlpb,
                                                 const unsigned short* __restrict__ mbuf,
                                                 float* __restrict__ hid) {
  const int mblk = blockIdx.x >> 4, kblk = blockIdx.x & 15;
  const int wid = threadIdx.x >> 6, lane = threadIdx.x & 63;
  const int l15 = lane & 15, lg = lane >> 4;
  const int kq = kblk * 3840 + wid * 960;

  f32x4 acc[2][2];
#pragma unroll
  for (int i = 0; i < 2; ++i)
#pragma unroll
    for (int j = 0; j < 2; ++j) acc[i][j] = (f32x4){0.f, 0.f, 0.f, 0.f};

  const unsigned short* ap0 = wmlpb + (size_t)(mblk * 32 + l15) * FEAT_ + kq + lg * 8;
  const unsigned short* ap1 = ap0 + (size_t)16 * FEAT_;
  const unsigned short* bp0 = mbuf + (size_t)l15 * FEAT_ + kq + lg * 8;
  const unsigned short* bp1 = bp0 + (size_t)16 * FEAT_;
  for (int kt = 0; kt < 30; ++kt) {
    short8 a0 = *(const short8*)(ap0 + kt * 32);
    short8 a1 = *(const short8*)(ap1 + kt * 32);
    short8 b0 = *(const short8*)(bp0 + kt * 32);
    short8 b1 = *(const short8*)(bp1 + kt * 32);
    acc[0][0] = __builtin_amdgcn_mfma_f32_16x16x32_bf16(a0, b0, acc[0][0], 0, 0, 0);
    acc[0][1] = __builtin_amdgcn_mfma_f32_16x16x32_bf16(a0, b1, acc[0][1], 0, 0, 0);
    acc[1][0] = __builtin_amdgcn_mfma_f32_16x16x32_bf16(a1, b0, acc[1][0], 0, 0, 0);
    acc[1][1] = __builtin_amdgcn_mfma_f32_16x16x32_bf16(a1, b1, acc[1][1], 0, 0, 0);
  }

  __shared__ float red[4][32][33];
#pragma unroll
  for (int mi = 0; mi < 2; ++mi)
#pragma unroll
    for (int ni = 0; ni < 2; ++ni)
#pragma unroll
      for (int j = 0; j < 4; ++j)
        red[wid][mi * 16 + lg * 4 + j][ni * 16 + l15] = acc[mi][ni][j];
  __syncthreads();

  int m = threadIdx.x >> 3, b4 = (threadIdx.x & 7) * 4;
#pragma unroll
  for (int k = 0; k < 4; ++k) {
    int bb = b4 + k;
    float s = red[0][m][bb] + red[1][m][bb] + red[2][m][bb] + red[3][m][bb];
    atomicAdd(&hid[(size_t)bb * MH_ + mblk * 32 + m], s);
  }
}

// ---------------------------------------------------------------------------
// K9: decoded = softmax( relu(hid+b_mlp) @ W_dec^T + b_dec ); penal = mean.
// ---------------------------------------------------------------------------
__global__ void k9_out(const float* __restrict__ hid, const float* __restrict__ b_mlp,
                       const float* __restrict__ W_dec, const float* __restrict__ b_dec,
                       const float* __restrict__ penp, float* __restrict__ out) {
  int tid = threadIdx.x;
  if (tid < 64) {
    int b = tid >> 1, c = tid & 1;
    const float* hp = hid + (size_t)b * MH_;
    const float* wp = W_dec + (size_t)c * MH_;
    float acc = b_dec[c];
    for (int k = 0; k < MH_; ++k) {
      float hk = fmaxf(hp[k] + b_mlp[k], 0.f);
      acc = fmaf(hk, wp[k], acc);
    }
    float other = __shfl_xor(acc, 1);
    float mx = fmaxf(acc, other);
    float e = __expf(acc - mx), eo = __expf(other - mx);
    out[b * 2 + c] = e / (e + eo);
  } else if (tid == 64) {
    float s = 0.f;
    for (int b = 0; b < B_; ++b) s += penp[b];
    out[64] = s * (1.f / 32.f);
  }
}

// ---------------------------------------------------------------------------
extern "C" void kernel_launch(void* const* d_in, const int* in_sizes, int n_in,
                              void* d_out, int out_size, void* d_ws, size_t ws_size,
                              hipStream_t stream) {
  const int* inp = (const int*)d_in[0];
  const int* lens = (const int*)d_in[1];
  const float* W_emb = (const float*)d_in[2];
  const float* W_ih = (const float*)d_in[3];
  const float* W_hh = (const float*)d_in[4];
  const float* b_ih = (const float*)d_in[5];
  const float* b_hh = (const float*)d_in[6];
  const float* W1 = (const float*)d_in[7];
  const float* W2 = (const float*)d_in[8];
  const float* W_mlp = (const float*)d_in[9];
  const float* b_mlp = (const float*)d_in[10];
  const float* W_dec = (const float*)d_in[11];
  const float* b_dec = (const float*)d_in[12];
  float* out = (float*)d_out;

  char* ws = (char*)d_ws;
  size_t off = 0;
  auto take = [&](size_t bytes) -> char* {
    char* p = ws + off;
    off = (off + bytes + 255) & ~(size_t)255;
    return p;
  };
  unsigned short* outb = (unsigned short*)take((size_t)B_ * T_ * 2048 * 2);     // 67.1 MB
  unsigned short* hpub = (unsigned short*)take((size_t)2 * T_ * 32768 * 2);     // 67.1 MB
  unsigned short* xb = (unsigned short*)take((size_t)16384 * KE_ * 2);          // 12.6 MB
  unsigned short* wihb = (unsigned short*)take((size_t)8192 * KE_ * 2);         // 6.3 MB
  unsigned short* w1b = (unsigned short*)take((size_t)AC_ * 2048 * 2);          // 1.6 MB
  unsigned short* wmlpb = (unsigned short*)take((size_t)MH_ * FEAT_ * 2);       // 62.9 MB
  unsigned short* th1 = (unsigned short*)take((size_t)16384 * AC_ * 2);         // 12.6 MB
  float* abuf = (float*)take((size_t)B_ * R_ * T_ * 4);                         // 2.0 MB
  unsigned short* mbuf = (unsigned short*)take((size_t)B_ * FEAT_ * 2);         // 3.9 MB
  float* penp = (float*)take(B_ * 4);
  float* hid = (float*)take((size_t)B_ * MH_ * 4);

  if (off > ws_size) {  // unambiguous failure signal: NaN output
    hipMemsetAsync(d_out, 0xFF, (size_t)out_size * 4, stream);
    return;
  }

  // sentinel-init hpub: 0xFFFF bf16 has bit14 set => "unwritten" marker
  hipMemsetAsync(hpub, 0xFF, (size_t)2 * T_ * 32768 * 2, stream);
  hipMemsetAsync(hid, 0, (size_t)B_ * MH_ * 4, stream);

  k0_prep<<<2048, 256, 0, stream>>>(inp, W_emb, W_ih, W1, W_mlp, xb, wihb, w1b, wmlpb);
  k2_rnn<<<128, 256, 0, stream>>>(W_hh, wihb, xb, b_ih, b_hh, outb, hpub);
  k3_s1<<<512, 256, 0, stream>>>(outb, w1b, th1);
  k4_s2<<<2048, 256, 0, stream>>>(th1, W2, abuf);
  k5_sm<<<240, 256, 0, stream>>>(abuf, lens);
  k6_m<<<512, 256, 0, stream>>>(abuf, outb, mbuf);
  k7_pen<<<32, 256, 0, stream>>>(abuf, penp);
  k8_mlp<<<256, 256, 0, stream>>>(wmlpb, mbuf, hid);
  k9_out<<<1, 128, 0, stream>>>(hid, b_mlp, W_dec, b_dec, penp, out);
}

// Round 13
// 2142.726 us; speedup vs baseline: 1.9575x; 1.0564x over previous
//
#include <hip/hip_runtime.h>
#include <stdint.h>

typedef __attribute__((ext_vector_type(8))) short short8;
typedef __attribute__((ext_vector_type(4))) float f32x4;
typedef __attribute__((ext_vector_type(4))) unsigned int u32x4;

#define B_    32
#define T_    512
#define E_    300
#define KE_   384     // padded embed K (multiple of 128 for 4-wave x 32 split)
#define H_    1024
#define G4_   4096
#define R_    30
#define AD_   350
#define AC_   384
#define MH_   512
#define FEAT_ 61440
#define NWG_  64      // workgroups per direction
#define NU_   16      // hidden units per workgroup
#define DTICK 16ull   // pacing delta: ~0.64us @ 25MHz RTC (covers line visibility)

__device__ __forceinline__ unsigned short f2bu(float f) {
  unsigned int x = __builtin_bit_cast(unsigned int, f);
  x += 0x7fffu + ((x >> 16) & 1u);
  return (unsigned short)(x >> 16);
}
__device__ __forceinline__ float b2f(unsigned short u) {
  return __builtin_bit_cast(float, (unsigned int)u << 16);
}
__device__ __forceinline__ float sigm(float x) {
  return __builtin_amdgcn_rcpf(1.f + __expf(-x));
}
__device__ __forceinline__ float tanh_fast(float x) {
  return 1.f - 2.f * __builtin_amdgcn_rcpf(1.f + __expf(2.f * x));
}

// Gathered 16x dwordx4 ISSUE (no waitcnt) of the wave's B-frags from hpub.
#define BULK16G_ISS(b0p, b1p, b2p, b3p, FL)                                     \
  asm volatile(                                                                 \
      "global_load_dwordx4 %0, %16, off " FL "\n\t"                             \
      "global_load_dwordx4 %1, %16, off offset:2048 " FL "\n\t"                 \
      "global_load_dwordx4 %2, %17, off " FL "\n\t"                             \
      "global_load_dwordx4 %3, %17, off offset:2048 " FL "\n\t"                 \
      "global_load_dwordx4 %4, %18, off " FL "\n\t"                             \
      "global_load_dwordx4 %5, %18, off offset:2048 " FL "\n\t"                 \
      "global_load_dwordx4 %6, %19, off " FL "\n\t"                             \
      "global_load_dwordx4 %7, %19, off offset:2048 " FL "\n\t"                 \
      "global_load_dwordx4 %8, %16, off offset:512 " FL "\n\t"                  \
      "global_load_dwordx4 %9, %16, off offset:2560 " FL "\n\t"                 \
      "global_load_dwordx4 %10, %17, off offset:512 " FL "\n\t"                 \
      "global_load_dwordx4 %11, %17, off offset:2560 " FL "\n\t"                \
      "global_load_dwordx4 %12, %18, off offset:512 " FL "\n\t"                 \
      "global_load_dwordx4 %13, %18, off offset:2560 " FL "\n\t"                \
      "global_load_dwordx4 %14, %19, off offset:512 " FL "\n\t"                 \
      "global_load_dwordx4 %15, %19, off offset:2560 " FL                       \
      : "=&v"(q0), "=&v"(q1), "=&v"(q2), "=&v"(q3), "=&v"(q4), "=&v"(q5),       \
        "=&v"(q6), "=&v"(q7), "=&v"(q8), "=&v"(q9), "=&v"(qa), "=&v"(qb),       \
        "=&v"(qc), "=&v"(qd), "=&v"(qe), "=&v"(qf)                              \
      : "v"(b0p), "v"(b1p), "v"(b2p), "v"(b3p)                                  \
      : "memory")

#define BULK16G(b0p, b1p, b2p, b3p, FL)                                         \
  do {                                                                          \
    BULK16G_ISS(b0p, b1p, b2p, b3p, FL);                                        \
    asm volatile("s_waitcnt vmcnt(0)" ::: "memory");                            \
    __builtin_amdgcn_sched_barrier(0);                                          \
  } while (0)

// validate: any bf16 half with bit14 set => sentinel/unwritten
#define VAL16(BAD)                                                              \
  {                                                                             \
    u32x4 o01 = q0 | q1, o23 = q2 | q3, o45 = q4 | q5, o67 = q6 | q7;           \
    u32x4 o89 = q8 | q9, oab = qa | qb, ocd = qc | qd, oef = qe | qf;           \
    u32x4 ov4 = ((o01 | o23) | (o45 | o67)) | ((o89 | oab) | (ocd | oef));      \
    unsigned ovv = (ov4[0] | ov4[1]) | (ov4[2] | ov4[3]);                       \
    BAD = (ovv & 0x40004000u) != 0;                                             \
  }

// ---------------------------------------------------------------------------
// K0: cast/pad to bf16: xb[16384][384], wihb[8192][384], w1b[384][2048],
//     wmlpb[512][61440]
// ---------------------------------------------------------------------------
__global__ void k0_prep(const int* __restrict__ inp, const float* __restrict__ W_emb,
                        const float* __restrict__ W_ih, const float* __restrict__ W1,
                        const float* __restrict__ W_mlp,
                        unsigned short* __restrict__ xb, unsigned short* __restrict__ wihb,
                        unsigned short* __restrict__ w1b, unsigned short* __restrict__ wmlpb) {
  const int N1 = 16384 * KE_;
  const int N2 = 8192 * KE_;
  const int N3 = AC_ * 2048;
  const int N4 = MH_ * FEAT_;
  const int NT = N1 + N2 + N3 + N4;
  for (int i = blockIdx.x * blockDim.x + threadIdx.x; i < NT; i += gridDim.x * blockDim.x) {
    if (i < N1) {
      int row = i / KE_, e = i - row * KE_;
      float v = (e < E_) ? W_emb[(size_t)inp[row] * E_ + e] : 0.f;
      xb[i] = f2bu(v);
    } else if (i < N1 + N2) {
      int j = i - N1;
      int rw = j / KE_, e = j - rw * KE_;
      float v = (e < E_) ? W_ih[(size_t)rw * E_ + e] : 0.f;
      wihb[j] = f2bu(v);
    } else if (i < N1 + N2 + N3) {
      int j = i - N1 - N2;
      int a = j >> 11, k = j & 2047;
      float v = (a < AD_) ? W1[(size_t)a * 2048 + k] : 0.f;
      w1b[j] = f2bu(v);
    } else {
      int j = i - N1 - N2 - N3;
      wmlpb[j] = f2bu(W_mlp[j]);
    }
  }
}

// ---------------------------------------------------------------------------
// K2 v13: v12 (contiguous hpub rendezvous, clock-paced speculative load)
//   + DTICK 27->16 (single-writer lines need only ~0.5us visibility)
//   + payload-issue / x-GEMM-tail / waitcnt overlap (hides load latency)
// ---------------------------------------------------------------------------
__global__ __launch_bounds__(256, 1) void k2_rnn(const float* __restrict__ Whh,
                                                 const unsigned short* __restrict__ wihb,
                                                 const unsigned short* __restrict__ xb,
                                                 const float* __restrict__ b_ih,
                                                 const float* __restrict__ b_hh,
                                                 unsigned short* __restrict__ outb,
                                                 unsigned short* __restrict__ hpub) {
  const int dir = blockIdx.x >> 6;
  const int w = blockIdx.x & 63;
  const int tid = threadIdx.x;
  const int wid = tid >> 6, lane = tid & 63;
  const int l15 = lane & 15, lg = lane >> 4;

  __shared__ float Gp[4][4][32][21];               // [wave][gate][batch][unit+pad21]
  __shared__ __align__(16) unsigned short htmp[32][16];

  // ---- preload W_hh K-quarter as bf16 A-frags --------------------------
  short8 afr[4][8];
  {
    const int kq = wid << 8;
#pragma unroll
    for (int g = 0; g < 4; ++g) {
      const float* wp = Whh + ((size_t)dir * G4_ + g * H_ + w * NU_ + l15) * H_ + kq + lg * 8;
#pragma unroll
      for (int ktl = 0; ktl < 8; ++ktl) {
        float4 f0 = *(const float4*)(wp + ktl * 32);
        float4 f1 = *(const float4*)(wp + ktl * 32 + 4);
        short8 s;
        s[0] = (short)f2bu(f0.x); s[1] = (short)f2bu(f0.y);
        s[2] = (short)f2bu(f0.z); s[3] = (short)f2bu(f0.w);
        s[4] = (short)f2bu(f1.x); s[5] = (short)f2bu(f1.y);
        s[6] = (short)f2bu(f1.z); s[7] = (short)f2bu(f1.w);
        afr[g][ktl] = s;
      }
    }
  }

  // ---- preload W_ih K-slice (96 of 384) as bf16 A-frags ----------------
  const int kqx = wid * 96;
  short8 axr[4][3];
#pragma unroll
  for (int g = 0; g < 4; ++g) {
    const unsigned short* xp = wihb + ((size_t)dir * G4_ + g * H_ + w * NU_ + l15) * KE_ + kqx + lg * 8;
#pragma unroll
    for (int kt = 0; kt < 3; ++kt) axr[g][kt] = *(const short8*)(xp + kt * 32);
  }

  const int u = tid >> 5;    // activation role: unit pair (u, u+8)
  const int b = tid & 31;    // activation role: batch

  float bsum[2][4];
#pragma unroll
  for (int p = 0; p < 2; ++p)
#pragma unroll
    for (int g = 0; g < 4; ++g) {
      int row = dir * G4_ + g * H_ + w * NU_ + u + p * 8;
      bsum[p][g] = b_ih[row] + b_hh[row];
    }

  // hpub gather base (per wave/lane): chunk = (dir,t,w) of 512 ushorts.
  const size_t hlane = (size_t)wid * 8192 + (size_t)(lg >> 1) * 512 + l15 * 16 + (lg & 1) * 8;
  const size_t hpoll = (size_t)lane * 512;

  float cst[2] = {0.f, 0.f};
  unsigned long long pprev = __builtin_amdgcn_s_memrealtime();

#pragma unroll 1
  for (int s = 0; s < T_; ++s) {
    const int t = dir ? (T_ - 1 - s) : s;

    f32x4 acc[4][2];
#pragma unroll
    for (int g = 0; g < 4; ++g) {
      acc[g][0] = (f32x4){0.f, 0.f, 0.f, 0.f};
      acc[g][1] = (f32x4){0.f, 0.f, 0.f, 0.f};
    }

    // -- x-GEMM part 1 (kt=0,1): fills the pacing window ------------------
    short8 xbf[2][3];
#pragma unroll
    for (int n = 0; n < 2; ++n)
#pragma unroll
      for (int kt = 0; kt < 3; ++kt)
        xbf[n][kt] = *(const short8*)(xb + ((size_t)(n * 16 + l15) * T_ + t) * KE_ + kqx + kt * 32 + lg * 8);
#pragma unroll
    for (int kt = 0; kt < 2; ++kt)
#pragma unroll
      for (int g = 0; g < 4; ++g) {
        acc[g][0] = __builtin_amdgcn_mfma_f32_16x16x32_bf16(axr[g][kt], xbf[0][kt], acc[g][0], 0, 0, 0);
        acc[g][1] = __builtin_amdgcn_mfma_f32_16x16x32_bf16(axr[g][kt], xbf[1][kt], acc[g][1], 0, 0, 0);
      }
    __builtin_amdgcn_sched_barrier(0);

    if (s > 0) {
      const int tsrc = dir ? t + 1 : t - 1;
      const unsigned short* hbase = hpub + (size_t)(dir * T_ + tsrc) * 32768;
      const unsigned short* B0 = hbase + hlane;
      const unsigned short* B1 = B0 + 2048;
      const unsigned short* B2 = B0 + 4096;
      const unsigned short* B3 = B0 + 6144;
      u32x4 q0, q1, q2, q3, q4, q5, q6, q7, q8, q9, qa, qb, qc, qd, qe, qf;

      // -- pace: spin on scalar clock until own prev publish + DTICK ------
      {
        unsigned long long tgt = pprev + DTICK;
        unsigned long long now;
        do { now = __builtin_amdgcn_s_memrealtime(); } while (now < tgt);
      }

      // -- speculative payload: ISSUE, overlap x-GEMM tail, then wait -----
      BULK16G_ISS(B0, B1, B2, B3, "sc0");
      __builtin_amdgcn_sched_barrier(0);
#pragma unroll
      for (int g = 0; g < 4; ++g) {     // x-GEMM part 2 (kt=2) hides latency
        acc[g][0] = __builtin_amdgcn_mfma_f32_16x16x32_bf16(axr[g][2], xbf[0][2], acc[g][0], 0, 0, 0);
        acc[g][1] = __builtin_amdgcn_mfma_f32_16x16x32_bf16(axr[g][2], xbf[1][2], acc[g][1], 0, 0, 0);
      }
      __builtin_amdgcn_sched_barrier(0);
      asm volatile("s_waitcnt vmcnt(0)" ::: "memory");
      __builtin_amdgcn_sched_barrier(0);

      bool bad; VAL16(bad);
      if (__builtin_expect(bad, 0)) {
        // backstop: thin-poll the 64 producers, then gather-retry (MALL)
        const unsigned short* sp = hbase + hpoll;
        unsigned v;
        int guard = 0;
        for (;;) {
          asm volatile("global_load_dword %0, %1, off sc0 sc1\n\ts_waitcnt vmcnt(0)"
                       : "=v"(v) : "v"(sp) : "memory");
          if (__all(!(v & 0x40004000u))) break;
          if (++guard > 50000) break;   // hang safety; never trips co-resident
        }
        int g2 = 0;
        do {
          BULK16G(B0, B1, B2, B3, "sc0 sc1");
          VAL16(bad);
        } while (bad && ++g2 < 50000);
      }

      short8 bf0[8], bf1[8];
      bf0[0] = __builtin_bit_cast(short8, q0); bf0[1] = __builtin_bit_cast(short8, q1);
      bf0[2] = __builtin_bit_cast(short8, q2); bf0[3] = __builtin_bit_cast(short8, q3);
      bf0[4] = __builtin_bit_cast(short8, q4); bf0[5] = __builtin_bit_cast(short8, q5);
      bf0[6] = __builtin_bit_cast(short8, q6); bf0[7] = __builtin_bit_cast(short8, q7);
      bf1[0] = __builtin_bit_cast(short8, q8); bf1[1] = __builtin_bit_cast(short8, q9);
      bf1[2] = __builtin_bit_cast(short8, qa); bf1[3] = __builtin_bit_cast(short8, qb);
      bf1[4] = __builtin_bit_cast(short8, qc); bf1[5] = __builtin_bit_cast(short8, qd);
      bf1[6] = __builtin_bit_cast(short8, qe); bf1[7] = __builtin_bit_cast(short8, qf);

#pragma unroll
      for (int ktl = 0; ktl < 8; ++ktl) {
#pragma unroll
        for (int g = 0; g < 4; ++g) {
          acc[g][0] = __builtin_amdgcn_mfma_f32_16x16x32_bf16(afr[g][ktl], bf0[ktl], acc[g][0], 0, 0, 0);
          acc[g][1] = __builtin_amdgcn_mfma_f32_16x16x32_bf16(afr[g][ktl], bf1[ktl], acc[g][1], 0, 0, 0);
        }
      }
    } else {
      // s == 0: finish x-GEMM (kt=2) with no h-term
#pragma unroll
      for (int g = 0; g < 4; ++g) {
        acc[g][0] = __builtin_amdgcn_mfma_f32_16x16x32_bf16(axr[g][2], xbf[0][2], acc[g][0], 0, 0, 0);
        acc[g][1] = __builtin_amdgcn_mfma_f32_16x16x32_bf16(axr[g][2], xbf[1][2], acc[g][1], 0, 0, 0);
      }
    }

    // -- write K-partial sums to LDS (scalar, stride-21: conflict-free) --
#pragma unroll
    for (int g = 0; g < 4; ++g)
#pragma unroll
      for (int n = 0; n < 2; ++n)
#pragma unroll
        for (int j = 0; j < 4; ++j)
          Gp[wid][g][n * 16 + l15][lg * 4 + j] = acc[g][n][j];
    __syncthreads();

    // -- activations: thread handles (u,b) and (u+8,b) -------------------
#pragma unroll
    for (int p = 0; p < 2; ++p) {
      int ul = u + p * 8;
      float gi = Gp[0][0][b][ul] + Gp[1][0][b][ul] + Gp[2][0][b][ul] + Gp[3][0][b][ul] + bsum[p][0];
      float gf = Gp[0][1][b][ul] + Gp[1][1][b][ul] + Gp[2][1][b][ul] + Gp[3][1][b][ul] + bsum[p][1];
      float gg = Gp[0][2][b][ul] + Gp[1][2][b][ul] + Gp[2][2][b][ul] + Gp[3][2][b][ul] + bsum[p][2];
      float go = Gp[0][3][b][ul] + Gp[1][3][b][ul] + Gp[2][3][b][ul] + Gp[3][3][b][ul] + bsum[p][3];
      cst[p] = sigm(gf) * cst[p] + sigm(gi) * tanh_fast(gg);
      float hv = sigm(go) * tanh_fast(cst[p]);
      htmp[b][ul] = f2bu(hv);
    }
    __syncthreads();

    // -- record anchor; wave 0 publishes: hpub (contiguous 1KB, sc0 sc1)
    //    gates the rendezvous; outb (plain cached) feeds k3/k6 later. -----
    pprev = __builtin_amdgcn_s_memrealtime();
    if (tid < 64) {
      int bb = tid >> 1, half = tid & 1;
      u32x4 v = *(const u32x4*)&htmp[bb][half * 8];
      unsigned short* hp = hpub + (size_t)(dir * T_ + t) * 32768 + (size_t)w * 512 + bb * 16 + half * 8;
      asm volatile("global_store_dwordx4 %0, %1, off sc0 sc1" :: "v"(hp), "v"(v) : "memory");
      *(u32x4*)(outb + ((size_t)bb * T_ + t) * 2048 + dir * H_ + w * NU_ + half * 8) = v;
    }
  }
}

// ---------------------------------------------------------------------------
// K3: th1[row][a] = tanh( out[row][:] . W1b[a][:] )
// ---------------------------------------------------------------------------
__global__ __launch_bounds__(256, 1) void k3_s1(const unsigned short* __restrict__ outb,
                                                const unsigned short* __restrict__ w1b,
                                                unsigned short* __restrict__ th1) {
  const int rb = blockIdx.x;
  const int wid = threadIdx.x >> 6, lane = threadIdx.x & 63;
  const int m = wid & 1, nh = wid >> 1;
  const int l15 = lane & 15, lg = lane >> 4;

  f32x4 acc[12];
#pragma unroll
  for (int nt = 0; nt < 12; ++nt) acc[nt] = (f32x4){0.f, 0.f, 0.f, 0.f};

  const unsigned short* arow = outb + ((size_t)rb * 32 + m * 16 + l15) * 2048;
  for (int kt = 0; kt < 64; ++kt) {
    short8 af = *(const short8*)(arow + kt * 32 + lg * 8);
#pragma unroll
    for (int nt = 0; nt < 12; ++nt) {
      int col = nh * 192 + nt * 16 + l15;
      short8 bf = *(const short8*)(w1b + (size_t)col * 2048 + kt * 32 + lg * 8);
      acc[nt] = __builtin_amdgcn_mfma_f32_16x16x32_bf16(af, bf, acc[nt], 0, 0, 0);
    }
  }
#pragma unroll
  for (int nt = 0; nt < 12; ++nt) {
#pragma unroll
    for (int j = 0; j < 4; ++j) {
      int row = rb * 32 + m * 16 + lg * 4 + j;
      int col = nh * 192 + nt * 16 + l15;
      th1[(size_t)row * AC_ + col] = f2bu(tanh_fast(acc[nt][j]));
    }
  }
}

// ---------------------------------------------------------------------------
// K4: abuf[b][r][t] = th1[row][:350] . W2[r][:350]
// ---------------------------------------------------------------------------
__global__ void k4_s2(const unsigned short* __restrict__ th1, const float* __restrict__ W2,
                      float* __restrict__ abuf) {
  int idx = blockIdx.x * 256 + threadIdx.x;
  int row = idx >> 5, r = idx & 31;
  if (r >= R_) return;
  const unsigned short* tp = th1 + (size_t)row * AC_;
  const float* wp = W2 + r * AD_;
  float acc = 0.f;
  for (int a = 0; a < AD_; ++a) acc = fmaf(b2f(tp[a]), wp[a], acc);
  int b = row >> 9, t = row & 511;
  abuf[((size_t)b * R_ + r) * T_ + t] = acc;
}

// ---------------------------------------------------------------------------
// K5: masked softmax over t (in place).  One wave per (b,r).
// ---------------------------------------------------------------------------
__global__ void k5_sm(float* __restrict__ abuf, const int* __restrict__ lens) {
  int wv = blockIdx.x * 4 + (threadIdx.x >> 6);
  int lane = threadIdx.x & 63;
  if (wv >= B_ * R_) return;
  int b = wv / R_, r = wv % R_;
  int len = lens[b];
  float* row = abuf + ((size_t)b * R_ + r) * T_;
  float v[8];
  float mx = -1e30f;
#pragma unroll
  for (int i = 0; i < 8; ++i) {
    int t = lane + i * 64;
    float x = (t < len) ? row[t] : -1e30f;
    v[i] = x;
    mx = fmaxf(mx, x);
  }
#pragma unroll
  for (int o = 32; o > 0; o >>= 1) mx = fmaxf(mx, __shfl_xor(mx, o));
  float sum = 0.f;
#pragma unroll
  for (int i = 0; i < 8; ++i) {
    float e = (v[i] > -1e29f) ? __expf(v[i] - mx) : 0.f;
    v[i] = e;
    sum += e;
  }
#pragma unroll
  for (int o = 32; o > 0; o >>= 1) sum += __shfl_xor(sum, o);
  float inv = 1.f / sum;
#pragma unroll
  for (int i = 0; i < 8; ++i) row[lane + i * 64] = v[i] * inv;
}

// ---------------------------------------------------------------------------
// K6: M[b][r][h] = sum_t A[b][r][t] * out[b][t][h].  Writes mbuf as bf16.
// ---------------------------------------------------------------------------
__global__ __launch_bounds__(256) void k6_m(const float* __restrict__ abuf,
                                            const unsigned short* __restrict__ outb,
                                            unsigned short* __restrict__ mbuf) {
  int b = blockIdx.x >> 4, hb = blockIdx.x & 15;
  __shared__ float As[R_ * T_];
  for (int i = threadIdx.x; i < R_ * T_; i += 256) As[i] = abuf[(size_t)b * R_ * T_ + i];
  __syncthreads();
  int h = threadIdx.x & 127, rh = threadIdx.x >> 7;
  float acc[15];
#pragma unroll
  for (int rr = 0; rr < 15; ++rr) acc[rr] = 0.f;
  const unsigned short* op = outb + (size_t)b * T_ * 2048 + hb * 128 + h;
  for (int t = 0; t < T_; ++t) {
    float vv = b2f(op[(size_t)t * 2048]);
#pragma unroll
    for (int rr = 0; rr < 15; ++rr) acc[rr] = fmaf(As[(rh * 15 + rr) * T_ + t], vv, acc[rr]);
  }
#pragma unroll
  for (int rr = 0; rr < 15; ++rr)
    mbuf[(size_t)b * FEAT_ + (size_t)(rh * 15 + rr) * 2048 + hb * 128 + h] = f2bu(acc[rr]);
}

// ---------------------------------------------------------------------------
// K7: per-sample penalty partial: ||A A^T - I||_F^2.
// ---------------------------------------------------------------------------
__global__ __launch_bounds__(256) void k7_pen(const float* __restrict__ abuf,
                                              float* __restrict__ penp) {
  int b = blockIdx.x;
  __shared__ float As[R_ * 515];
  __shared__ float red[256];
  for (int i = threadIdx.x; i < R_ * T_; i += 256) {
    int r = i >> 9, t = i & 511;
    As[r * 515 + t] = abuf[(size_t)b * R_ * T_ + i];
  }
  __syncthreads();
  float psum = 0.f;
  for (int p = threadIdx.x; p < R_ * R_; p += 256) {
    int r = p / R_, s = p % R_;
    const float* pr = As + r * 515;
    const float* ps = As + s * 515;
    float d = 0.f;
    for (int t = 0; t < T_; ++t) d = fmaf(pr[t], ps[t], d);
    d -= (r == s) ? 1.f : 0.f;
    psum += d * d;
  }
  red[threadIdx.x] = psum;
  __syncthreads();
  for (int o = 128; o > 0; o >>= 1) {
    if (threadIdx.x < o) red[threadIdx.x] += red[threadIdx.x + o];
    __syncthreads();
  }
  if (threadIdx.x == 0) penp[b] = red[0];
}

// ---------------------------------------------------------------------------
// K8 v2: hidsum[b][m] += wmlpb[m-tile][k-tile] . mbuf[b][k-tile]  (MFMA)
// ---------------------------------------------------------------------------
__global__ __launch_bounds__(256, 1) void k8_mlp(const unsigned short* __restrict__ wmlpb,
                                                 const unsigned short* __restrict__ mbuf,
                                                 float* __restrict__ hid) {
  const int mblk = blockIdx.x >> 4, kblk = blockIdx.x & 15;
  const int wid = threadIdx.x >> 6, lane = threadIdx.x & 63;
  const int l15 = lane & 15, lg = lane >> 4;
  const int kq = kblk * 3840 + wid * 960;

  f32x4 acc[2][2];
#pragma unroll
  for (int i = 0; i < 2; ++i)
#pragma unroll
    for (int j = 0; j < 2; ++j) acc[i][j] = (f32x4){0.f, 0.f, 0.f, 0.f};

  const unsigned short* ap0 = wmlpb + (size_t)(mblk * 32 + l15) * FEAT_ + kq + lg * 8;
  const unsigned short* ap1 = ap0 + (size_t)16 * FEAT_;
  const unsigned short* bp0 = mbuf + (size_t)l15 * FEAT_ + kq + lg * 8;
  const unsigned short* bp1 = bp0 + (size_t)16 * FEAT_;
  for (int kt = 0; kt < 30; ++kt) {
    short8 a0 = *(const short8*)(ap0 + kt * 32);
    short8 a1 = *(const short8*)(ap1 + kt * 32);
    short8 b0 = *(const short8*)(bp0 + kt * 32);
    short8 b1 = *(const short8*)(bp1 + kt * 32);
    acc[0][0] = __builtin_amdgcn_mfma_f32_16x16x32_bf16(a0, b0, acc[0][0], 0, 0, 0);
    acc[0][1] = __builtin_amdgcn_mfma_f32_16x16x32_bf16(a0, b1, acc[0][1], 0, 0, 0);
    acc[1][0] = __builtin_amdgcn_mfma_f32_16x16x32_bf16(a1, b0, acc[1][0], 0, 0, 0);
    acc[1][1] = __builtin_amdgcn_mfma_f32_16x16x32_bf16(a1, b1, acc[1][1], 0, 0, 0);
  }

  __shared__ float red[4][32][33];
#pragma unroll
  for (int mi = 0; mi < 2; ++mi)
#pragma unroll
    for (int ni = 0; ni < 2; ++ni)
#pragma unroll
      for (int j = 0; j < 4; ++j)
        red[wid][mi * 16 + lg * 4 + j][ni * 16 + l15] = acc[mi][ni][j];
  __syncthreads();

  int m = threadIdx.x >> 3, b4 = (threadIdx.x & 7) * 4;
#pragma unroll
  for (int k = 0; k < 4; ++k) {
    int bb = b4 + k;
    float s = red[0][m][bb] + red[1][m][bb] + red[2][m][bb] + red[3][m][bb];
    atomicAdd(&hid[(size_t)bb * MH_ + mblk * 32 + m], s);
  }
}

// ---------------------------------------------------------------------------
// K9: decoded = softmax( relu(hid+b_mlp) @ W_dec^T + b_dec ); penal = mean.
// ---------------------------------------------------------------------------
__global__ void k9_out(const float* __restrict__ hid, const float* __restrict__ b_mlp,
                       const float* __restrict__ W_dec, const float* __restrict__ b_dec,
                       const float* __restrict__ penp, float* __restrict__ out) {
  int tid = threadIdx.x;
  if (tid < 64) {
    int b = tid >> 1, c = tid & 1;
    const float* hp = hid + (size_t)b * MH_;
    const float* wp = W_dec + (size_t)c * MH_;
    float acc = b_dec[c];
    for (int k = 0; k < MH_; ++k) {
      float hk = fmaxf(hp[k] + b_mlp[k], 0.f);
      acc = fmaf(hk, wp[k], acc);
    }
    float other = __shfl_xor(acc, 1);
    float mx = fmaxf(acc, other);
    float e = __expf(acc - mx), eo = __expf(other - mx);
    out[b * 2 + c] = e / (e + eo);
  } else if (tid == 64) {
    float s = 0.f;
    for (int b = 0; b < B_; ++b) s += penp[b];
    out[64] = s * (1.f / 32.f);
  }
}

// ---------------------------------------------------------------------------
extern "C" void kernel_launch(void* const* d_in, const int* in_sizes, int n_in,
                              void* d_out, int out_size, void* d_ws, size_t ws_size,
                              hipStream_t stream) {
  const int* inp = (const int*)d_in[0];
  const int* lens = (const int*)d_in[1];
  const float* W_emb = (const float*)d_in[2];
  const float* W_ih = (const float*)d_in[3];
  const float* W_hh = (const float*)d_in[4];
  const float* b_ih = (const float*)d_in[5];
  const float* b_hh = (const float*)d_in[6];
  const float* W1 = (const float*)d_in[7];
  const float* W2 = (const float*)d_in[8];
  const float* W_mlp = (const float*)d_in[9];
  const float* b_mlp = (const float*)d_in[10];
  const float* W_dec = (const float*)d_in[11];
  const float* b_dec = (const float*)d_in[12];
  float* out = (float*)d_out;

  char* ws = (char*)d_ws;
  size_t off = 0;
  auto take = [&](size_t bytes) -> char* {
    char* p = ws + off;
    off = (off + bytes + 255) & ~(size_t)255;
    return p;
  };
  unsigned short* outb = (unsigned short*)take((size_t)B_ * T_ * 2048 * 2);     // 67.1 MB
  unsigned short* hpub = (unsigned short*)take((size_t)2 * T_ * 32768 * 2);     // 67.1 MB
  unsigned short* xb = (unsigned short*)take((size_t)16384 * KE_ * 2);          // 12.6 MB
  unsigned short* wihb = (unsigned short*)take((size_t)8192 * KE_ * 2);         // 6.3 MB
  unsigned short* w1b = (unsigned short*)take((size_t)AC_ * 2048 * 2);          // 1.6 MB
  unsigned short* wmlpb = (unsigned short*)take((size_t)MH_ * FEAT_ * 2);       // 62.9 MB
  unsigned short* th1 = (unsigned short*)take((size_t)16384 * AC_ * 2);         // 12.6 MB
  float* abuf = (float*)take((size_t)B_ * R_ * T_ * 4);                         // 2.0 MB
  unsigned short* mbuf = (unsigned short*)take((size_t)B_ * FEAT_ * 2);         // 3.9 MB
  float* penp = (float*)take(B_ * 4);
  float* hid = (float*)take((size_t)B_ * MH_ * 4);

  if (off > ws_size) {  // unambiguous failure signal: NaN output
    hipMemsetAsync(d_out, 0xFF, (size_t)out_size * 4, stream);
    return;
  }

  // sentinel-init hpub: 0xFFFF bf16 has bit14 set => "unwritten" marker
  hipMemsetAsync(hpub, 0xFF, (size_t)2 * T_ * 32768 * 2, stream);
  hipMemsetAsync(hid, 0, (size_t)B_ * MH_ * 4, stream);

  k0_prep<<<2048, 256, 0, stream>>>(inp, W_emb, W_ih, W1, W_mlp, xb, wihb, w1b, wmlpb);
  k2_rnn<<<128, 256, 0, stream>>>(W_hh, wihb, xb, b_ih, b_hh, outb, hpub);
  k3_s1<<<512, 256, 0, stream>>>(outb, w1b, th1);
  k4_s2<<<2048, 256, 0, stream>>>(th1, W2, abuf);
  k5_sm<<<240, 256, 0, stream>>>(abuf, lens);
  k6_m<<<512, 256, 0, stream>>>(abuf, outb, mbuf);
  k7_pen<<<32, 256, 0, stream>>>(abuf, penp);
  k8_mlp<<<256, 256, 0, stream>>>(wmlpb, mbuf, hid);
  k9_out<<<1, 128, 0, stream>>>(hid, b_mlp, W_dec, b_dec, penp, out);
}

// Round 14
// 2071.107 us; speedup vs baseline: 2.0252x; 1.0346x over previous
//
#include <hip/hip_runtime.h>
#include <stdint.h>

typedef __attribute__((ext_vector_type(8))) short short8;
typedef __attribute__((ext_vector_type(4))) float f32x4;
typedef __attribute__((ext_vector_type(4))) unsigned int u32x4;

#define B_    32
#define T_    512
#define E_    300
#define KE_   384     // padded embed K (4-wave x 96 split)
#define H_    1024
#define G4_   4096
#define R_    30
#define AD_   350
#define AC_   384
#define MH_   512
#define FEAT_ 61440
#define NU_   16      // hidden units per (dir,w) group
#define DTICK 16ull   // pacing delta: ~0.64us @ 25MHz RTC

__device__ __forceinline__ unsigned short f2bu(float f) {
  unsigned int x = __builtin_bit_cast(unsigned int, f);
  x += 0x7fffu + ((x >> 16) & 1u);
  return (unsigned short)(x >> 16);
}
__device__ __forceinline__ float b2f(unsigned short u) {
  return __builtin_bit_cast(float, (unsigned int)u << 16);
}
__device__ __forceinline__ float sigm(float x) {
  return __builtin_amdgcn_rcpf(1.f + __expf(-x));
}
__device__ __forceinline__ float tanh_fast(float x) {
  return 1.f - 2.f * __builtin_amdgcn_rcpf(1.f + __expf(2.f * x));
}

// 8x dwordx4 gather issue (no waitcnt): 2 bases x 4 imm offsets (ktl steps)
#define BULK8G_ISS(b0p, b1p, FL)                                                \
  asm volatile(                                                                 \
      "global_load_dwordx4 %0, %8, off " FL "\n\t"                              \
      "global_load_dwordx4 %1, %8, off offset:1024 " FL "\n\t"                  \
      "global_load_dwordx4 %2, %8, off offset:2048 " FL "\n\t"                  \
      "global_load_dwordx4 %3, %8, off offset:3072 " FL "\n\t"                  \
      "global_load_dwordx4 %4, %9, off " FL "\n\t"                              \
      "global_load_dwordx4 %5, %9, off offset:1024 " FL "\n\t"                  \
      "global_load_dwordx4 %6, %9, off offset:2048 " FL "\n\t"                  \
      "global_load_dwordx4 %7, %9, off offset:3072 " FL                         \
      : "=&v"(q0), "=&v"(q1), "=&v"(q2), "=&v"(q3),                             \
        "=&v"(q4), "=&v"(q5), "=&v"(q6), "=&v"(q7)                              \
      : "v"(b0p), "v"(b1p)                                                      \
      : "memory")

#define BULK8G(b0p, b1p, FL)                                                    \
  do {                                                                          \
    BULK8G_ISS(b0p, b1p, FL);                                                   \
    asm volatile("s_waitcnt vmcnt(0)" ::: "memory");                            \
    __builtin_amdgcn_sched_barrier(0);                                          \
  } while (0)

// validate: any bf16 half with bit14 set => sentinel/unwritten
#define VAL8(BAD)                                                               \
  {                                                                             \
    u32x4 o01 = q0 | q1, o23 = q2 | q3, o45 = q4 | q5, o67 = q6 | q7;           \
    u32x4 ov4 = (o01 | o23) | (o45 | o67);                                      \
    unsigned ovv = (ov4[0] | ov4[1]) | (ov4[2] | ov4[3]);                       \
    BAD = (ovv & 0x40004000u) != 0;                                             \
  }

// ---------------------------------------------------------------------------
// K0: cast/pad to bf16: xb[16384][384], wihb[8192][384], w1b[384][2048],
//     wmlpb[512][61440]
// ---------------------------------------------------------------------------
__global__ void k0_prep(const int* __restrict__ inp, const float* __restrict__ W_emb,
                        const float* __restrict__ W_ih, const float* __restrict__ W1,
                        const float* __restrict__ W_mlp,
                        unsigned short* __restrict__ xb, unsigned short* __restrict__ wihb,
                        unsigned short* __restrict__ w1b, unsigned short* __restrict__ wmlpb) {
  const int N1 = 16384 * KE_;
  const int N2 = 8192 * KE_;
  const int N3 = AC_ * 2048;
  const int N4 = MH_ * FEAT_;
  const int NT = N1 + N2 + N3 + N4;
  for (int i = blockIdx.x * blockDim.x + threadIdx.x; i < NT; i += gridDim.x * blockDim.x) {
    if (i < N1) {
      int row = i / KE_, e = i - row * KE_;
      float v = (e < E_) ? W_emb[(size_t)inp[row] * E_ + e] : 0.f;
      xb[i] = f2bu(v);
    } else if (i < N1 + N2) {
      int j = i - N1;
      int rw = j / KE_, e = j - rw * KE_;
      float v = (e < E_) ? W_ih[(size_t)rw * E_ + e] : 0.f;
      wihb[j] = f2bu(v);
    } else if (i < N1 + N2 + N3) {
      int j = i - N1 - N2;
      int a = j >> 11, k = j & 2047;
      float v = (a < AD_) ? W1[(size_t)a * 2048 + k] : 0.f;
      w1b[j] = f2bu(v);
    } else {
      int j = i - N1 - N2 - N3;
      wmlpb[j] = f2bu(W_mlp[j]);
    }
  }
}

// ---------------------------------------------------------------------------
// K2 v14: batch-split swarm.  256 WGs = (dir 2) x (w 64) x (bh 2); each WG
//   handles 16 units x 16 batch.  Per-WG work halves vs v13; all 256 CUs
//   engaged; per-consumer producer set stays 16 (same-bh chunks only).
//   Protocol: clock-paced speculative sc0 gather from producer-contiguous
//   512B chunks (single-writer lines), bit14 validate, thin-poll + sc0 sc1
//   backstop.  hpub chunk = [b16][u16] at [dir][t][bh][w].
// ---------------------------------------------------------------------------
__global__ __launch_bounds__(256, 1) void k2_rnn(const float* __restrict__ Whh,
                                                 const unsigned short* __restrict__ wihb,
                                                 const unsigned short* __restrict__ xb,
                                                 const float* __restrict__ b_ih,
                                                 const float* __restrict__ b_hh,
                                                 unsigned short* __restrict__ outb,
                                                 unsigned short* __restrict__ hpub) {
  const int dir = blockIdx.x >> 7;
  const int w = (blockIdx.x >> 1) & 63;
  const int bh = blockIdx.x & 1;
  const int tid = threadIdx.x;
  const int wid = tid >> 6, lane = tid & 63;
  const int l15 = lane & 15, lg = lane >> 4;

  __shared__ float Gp[4][4][16][17];               // [wave][gate][batch16][unit+pad]
  __shared__ __align__(16) unsigned short htmp[16][16];

  // ---- preload W_hh K-quarter as bf16 A-frags (units 0..15, 4 gates) ---
  short8 afr[4][8];
  {
    const int kq = wid << 8;
#pragma unroll
    for (int g = 0; g < 4; ++g) {
      const float* wp = Whh + ((size_t)dir * G4_ + g * H_ + w * NU_ + l15) * H_ + kq + lg * 8;
#pragma unroll
      for (int ktl = 0; ktl < 8; ++ktl) {
        float4 f0 = *(const float4*)(wp + ktl * 32);
        float4 f1 = *(const float4*)(wp + ktl * 32 + 4);
        short8 s;
        s[0] = (short)f2bu(f0.x); s[1] = (short)f2bu(f0.y);
        s[2] = (short)f2bu(f0.z); s[3] = (short)f2bu(f0.w);
        s[4] = (short)f2bu(f1.x); s[5] = (short)f2bu(f1.y);
        s[6] = (short)f2bu(f1.z); s[7] = (short)f2bu(f1.w);
        afr[g][ktl] = s;
      }
    }
  }

  // ---- preload W_ih K-slice (96 of 384) as bf16 A-frags ----------------
  const int kqx = wid * 96;
  short8 axr[4][3];
#pragma unroll
  for (int g = 0; g < 4; ++g) {
    const unsigned short* xp = wihb + ((size_t)dir * G4_ + g * H_ + w * NU_ + l15) * KE_ + kqx + lg * 8;
#pragma unroll
    for (int kt = 0; kt < 3; ++kt) axr[g][kt] = *(const short8*)(xp + kt * 32);
  }

  const int u = tid >> 4;    // activation role: unit 0..15
  const int b = tid & 15;    // activation role: batch-within-half 0..15

  float bsum[4];
#pragma unroll
  for (int g = 0; g < 4; ++g) {
    int row = dir * G4_ + g * H_ + w * NU_ + u;
    bsum[g] = b_ih[row] + b_hh[row];
  }

  // gather/poll offsets within a (dir,t,bh) slot of 64 chunks x 256 ushorts
  const size_t hlane = (size_t)(wid * 16 + (lg >> 1)) * 256 + l15 * 16 + (lg & 1) * 8;
  const size_t hpoll = (size_t)(wid * 16 + (lane & 15)) * 256;

  float cst = 0.f;
  unsigned long long pprev = __builtin_amdgcn_s_memrealtime();

#pragma unroll 1
  for (int s = 0; s < T_; ++s) {
    const int t = dir ? (T_ - 1 - s) : s;

    f32x4 acc[4];
#pragma unroll
    for (int g = 0; g < 4; ++g) acc[g] = (f32x4){0.f, 0.f, 0.f, 0.f};

    // -- x-GEMM (12 MFMAs): cols = batch bh*16+l15; fills pacing window --
    {
      short8 xbf[3];
#pragma unroll
      for (int kt = 0; kt < 3; ++kt)
        xbf[kt] = *(const short8*)(xb + ((size_t)(bh * 16 + l15) * T_ + t) * KE_ + kqx + kt * 32 + lg * 8);
#pragma unroll
      for (int kt = 0; kt < 3; ++kt)
#pragma unroll
        for (int g = 0; g < 4; ++g)
          acc[g] = __builtin_amdgcn_mfma_f32_16x16x32_bf16(axr[g][kt], xbf[kt], acc[g], 0, 0, 0);
    }
    __builtin_amdgcn_sched_barrier(0);

    if (s > 0) {
      const int tsrc = dir ? t + 1 : t - 1;
      const unsigned short* hbase = hpub + ((size_t)(dir * T_ + tsrc) * 2 + bh) * 16384;
      const unsigned short* B0 = hbase + hlane;
      const unsigned short* B1 = B0 + 4096;      // +8 chunks (ktl 4..7)
      u32x4 q0, q1, q2, q3, q4, q5, q6, q7;

      // -- pace: spin on scalar clock until own prev publish + DTICK ------
      {
        unsigned long long tgt = pprev + DTICK;
        unsigned long long now;
        do { now = __builtin_amdgcn_s_memrealtime(); } while (now < tgt);
      }

      // -- speculative payload: 8x dwordx4 sc0 gather, validate -----------
      BULK8G(B0, B1, "sc0");
      bool bad; VAL8(bad);
      if (__builtin_expect(bad, 0)) {
        // backstop: thin-poll this wave's 16 producer chunks, then retry
        const unsigned short* sp = hbase + hpoll;
        unsigned v;
        int guard = 0;
        for (;;) {
          asm volatile("global_load_dword %0, %1, off sc0 sc1\n\ts_waitcnt vmcnt(0)"
                       : "=v"(v) : "v"(sp) : "memory");
          if (__all(!(v & 0x40004000u))) break;
          if (++guard > 50000) break;   // hang safety; never trips co-resident
        }
        int g2 = 0;
        do {
          BULK8G(B0, B1, "sc0 sc1");
          VAL8(bad);
        } while (bad && ++g2 < 50000);
      }

      short8 bf[8];
      bf[0] = __builtin_bit_cast(short8, q0); bf[1] = __builtin_bit_cast(short8, q1);
      bf[2] = __builtin_bit_cast(short8, q2); bf[3] = __builtin_bit_cast(short8, q3);
      bf[4] = __builtin_bit_cast(short8, q4); bf[5] = __builtin_bit_cast(short8, q5);
      bf[6] = __builtin_bit_cast(short8, q6); bf[7] = __builtin_bit_cast(short8, q7);

#pragma unroll
      for (int ktl = 0; ktl < 8; ++ktl)
#pragma unroll
        for (int g = 0; g < 4; ++g)
          acc[g] = __builtin_amdgcn_mfma_f32_16x16x32_bf16(afr[g][ktl], bf[ktl], acc[g], 0, 0, 0);
    }

    // -- write K-partial sums to LDS -------------------------------------
#pragma unroll
    for (int g = 0; g < 4; ++g)
#pragma unroll
      for (int j = 0; j < 4; ++j)
        Gp[wid][g][l15][lg * 4 + j] = acc[g][j];
    __syncthreads();

    // -- activations: thread handles (u, b) ------------------------------
    {
      float gi = Gp[0][0][b][u] + Gp[1][0][b][u] + Gp[2][0][b][u] + Gp[3][0][b][u] + bsum[0];
      float gf = Gp[0][1][b][u] + Gp[1][1][b][u] + Gp[2][1][b][u] + Gp[3][1][b][u] + bsum[1];
      float gg = Gp[0][2][b][u] + Gp[1][2][b][u] + Gp[2][2][b][u] + Gp[3][2][b][u] + bsum[2];
      float go = Gp[0][3][b][u] + Gp[1][3][b][u] + Gp[2][3][b][u] + Gp[3][3][b][u] + bsum[3];
      cst = sigm(gf) * cst + sigm(gi) * tanh_fast(gg);
      float hv = sigm(go) * tanh_fast(cst);
      htmp[b][u] = f2bu(hv);
    }
    __syncthreads();

    // -- record anchor; wave 0 publishes chunk (512B contiguous) + outb --
    pprev = __builtin_amdgcn_s_memrealtime();
    if (tid < 64) {
      int bb = tid >> 2, q = tid & 3;
      uint2 v = *(const uint2*)&htmp[bb][q * 4];
      unsigned short* hp = hpub + ((size_t)(dir * T_ + t) * 2 + bh) * 16384 + (size_t)w * 256 + bb * 16 + q * 4;
      asm volatile("global_store_dwordx2 %0, %1, off sc0 sc1" :: "v"(hp), "v"(v) : "memory");
      *(uint2*)(outb + ((size_t)(bh * 16 + bb) * T_ + t) * 2048 + dir * H_ + w * NU_ + q * 4) = v;
    }
  }
}

// ---------------------------------------------------------------------------
// K3: th1[row][a] = tanh( out[row][:] . W1b[a][:] )
// ---------------------------------------------------------------------------
__global__ __launch_bounds__(256, 1) void k3_s1(const unsigned short* __restrict__ outb,
                                                const unsigned short* __restrict__ w1b,
                                                unsigned short* __restrict__ th1) {
  const int rb = blockIdx.x;
  const int wid = threadIdx.x >> 6, lane = threadIdx.x & 63;
  const int m = wid & 1, nh = wid >> 1;
  const int l15 = lane & 15, lg = lane >> 4;

  f32x4 acc[12];
#pragma unroll
  for (int nt = 0; nt < 12; ++nt) acc[nt] = (f32x4){0.f, 0.f, 0.f, 0.f};

  const unsigned short* arow = outb + ((size_t)rb * 32 + m * 16 + l15) * 2048;
  for (int kt = 0; kt < 64; ++kt) {
    short8 af = *(const short8*)(arow + kt * 32 + lg * 8);
#pragma unroll
    for (int nt = 0; nt < 12; ++nt) {
      int col = nh * 192 + nt * 16 + l15;
      short8 bf = *(const short8*)(w1b + (size_t)col * 2048 + kt * 32 + lg * 8);
      acc[nt] = __builtin_amdgcn_mfma_f32_16x16x32_bf16(af, bf, acc[nt], 0, 0, 0);
    }
  }
#pragma unroll
  for (int nt = 0; nt < 12; ++nt) {
#pragma unroll
    for (int j = 0; j < 4; ++j) {
      int row = rb * 32 + m * 16 + lg * 4 + j;
      int col = nh * 192 + nt * 16 + l15;
      th1[(size_t)row * AC_ + col] = f2bu(tanh_fast(acc[nt][j]));
    }
  }
}

// ---------------------------------------------------------------------------
// K4: abuf[b][r][t] = th1[row][:350] . W2[r][:350]
// ---------------------------------------------------------------------------
__global__ void k4_s2(const unsigned short* __restrict__ th1, const float* __restrict__ W2,
                      float* __restrict__ abuf) {
  int idx = blockIdx.x * 256 + threadIdx.x;
  int row = idx >> 5, r = idx & 31;
  if (r >= R_) return;
  const unsigned short* tp = th1 + (size_t)row * AC_;
  const float* wp = W2 + r * AD_;
  float acc = 0.f;
  for (int a = 0; a < AD_; ++a) acc = fmaf(b2f(tp[a]), wp[a], acc);
  int b = row >> 9, t = row & 511;
  abuf[((size_t)b * R_ + r) * T_ + t] = acc;
}

// ---------------------------------------------------------------------------
// K5: masked softmax over t (in place).  One wave per (b,r).
// ---------------------------------------------------------------------------
__global__ void k5_sm(float* __restrict__ abuf, const int* __restrict__ lens) {
  int wv = blockIdx.x * 4 + (threadIdx.x >> 6);
  int lane = threadIdx.x & 63;
  if (wv >= B_ * R_) return;
  int b = wv / R_, r = wv % R_;
  int len = lens[b];
  float* row = abuf + ((size_t)b * R_ + r) * T_;
  float v[8];
  float mx = -1e30f;
#pragma unroll
  for (int i = 0; i < 8; ++i) {
    int t = lane + i * 64;
    float x = (t < len) ? row[t] : -1e30f;
    v[i] = x;
    mx = fmaxf(mx, x);
  }
#pragma unroll
  for (int o = 32; o > 0; o >>= 1) mx = fmaxf(mx, __shfl_xor(mx, o));
  float sum = 0.f;
#pragma unroll
  for (int i = 0; i < 8; ++i) {
    float e = (v[i] > -1e29f) ? __expf(v[i] - mx) : 0.f;
    v[i] = e;
    sum += e;
  }
#pragma unroll
  for (int o = 32; o > 0; o >>= 1) sum += __shfl_xor(sum, o);
  float inv = 1.f / sum;
#pragma unroll
  for (int i = 0; i < 8; ++i) row[lane + i * 64] = v[i] * inv;
}

// ---------------------------------------------------------------------------
// K6: M[b][r][h] = sum_t A[b][r][t] * out[b][t][h].  Writes mbuf as bf16.
// ---------------------------------------------------------------------------
__global__ __launch_bounds__(256) void k6_m(const float* __restrict__ abuf,
                                            const unsigned short* __restrict__ outb,
                                            unsigned short* __restrict__ mbuf) {
  int b = blockIdx.x >> 4, hb = blockIdx.x & 15;
  __shared__ float As[R_ * T_];
  for (int i = threadIdx.x; i < R_ * T_; i += 256) As[i] = abuf[(size_t)b * R_ * T_ + i];
  __syncthreads();
  int h = threadIdx.x & 127, rh = threadIdx.x >> 7;
  float acc[15];
#pragma unroll
  for (int rr = 0; rr < 15; ++rr) acc[rr] = 0.f;
  const unsigned short* op = outb + (size_t)b * T_ * 2048 + hb * 128 + h;
  for (int t = 0; t < T_; ++t) {
    float vv = b2f(op[(size_t)t * 2048]);
#pragma unroll
    for (int rr = 0; rr < 15; ++rr) acc[rr] = fmaf(As[(rh * 15 + rr) * T_ + t], vv, acc[rr]);
  }
#pragma unroll
  for (int rr = 0; rr < 15; ++rr)
    mbuf[(size_t)b * FEAT_ + (size_t)(rh * 15 + rr) * 2048 + hb * 128 + h] = f2bu(acc[rr]);
}

// ---------------------------------------------------------------------------
// K7: per-sample penalty partial: ||A A^T - I||_F^2.
// ---------------------------------------------------------------------------
__global__ __launch_bounds__(256) void k7_pen(const float* __restrict__ abuf,
                                              float* __restrict__ penp) {
  int b = blockIdx.x;
  __shared__ float As[R_ * 515];
  __shared__ float red[256];
  for (int i = threadIdx.x; i < R_ * T_; i += 256) {
    int r = i >> 9, t = i & 511;
    As[r * 515 + t] = abuf[(size_t)b * R_ * T_ + i];
  }
  __syncthreads();
  float psum = 0.f;
  for (int p = threadIdx.x; p < R_ * R_; p += 256) {
    int r = p / R_, s = p % R_;
    const float* pr = As + r * 515;
    const float* ps = As + s * 515;
    float d = 0.f;
    for (int t = 0; t < T_; ++t) d = fmaf(pr[t], ps[t], d);
    d -= (r == s) ? 1.f : 0.f;
    psum += d * d;
  }
  red[threadIdx.x] = psum;
  __syncthreads();
  for (int o = 128; o > 0; o >>= 1) {
    if (threadIdx.x < o) red[threadIdx.x] += red[threadIdx.x + o];
    __syncthreads();
  }
  if (threadIdx.x == 0) penp[b] = red[0];
}

// ---------------------------------------------------------------------------
// K8 v2: hidsum[b][m] += wmlpb[m-tile][k-tile] . mbuf[b][k-tile]  (MFMA)
// ---------------------------------------------------------------------------
__global__ __launch_bounds__(256, 1) void k8_mlp(const unsigned short* __restrict__ wmlpb,
                                                 const unsigned short* __restrict__ mbuf,
                                                 float* __restrict__ hid) {
  const int mblk = blockIdx.x >> 4, kblk = blockIdx.x & 15;
  const int wid = threadIdx.x >> 6, lane = threadIdx.x & 63;
  const int l15 = lane & 15, lg = lane >> 4;
  const int kq = kblk * 3840 + wid * 960;

  f32x4 acc[2][2];
#pragma unroll
  for (int i = 0; i < 2; ++i)
#pragma unroll
    for (int j = 0; j < 2; ++j) acc[i][j] = (f32x4){0.f, 0.f, 0.f, 0.f};

  const unsigned short* ap0 = wmlpb + (size_t)(mblk * 32 + l15) * FEAT_ + kq + lg * 8;
  const unsigned short* ap1 = ap0 + (size_t)16 * FEAT_;
  const unsigned short* bp0 = mbuf + (size_t)l15 * FEAT_ + kq + lg * 8;
  const unsigned short* bp1 = bp0 + (size_t)16 * FEAT_;
  for (int kt = 0; kt < 30; ++kt) {
    short8 a0 = *(const short8*)(ap0 + kt * 32);
    short8 a1 = *(const short8*)(ap1 + kt * 32);
    short8 b0 = *(const short8*)(bp0 + kt * 32);
    short8 b1 = *(const short8*)(bp1 + kt * 32);
    acc[0][0] = __builtin_amdgcn_mfma_f32_16x16x32_bf16(a0, b0, acc[0][0], 0, 0, 0);
    acc[0][1] = __builtin_amdgcn_mfma_f32_16x16x32_bf16(a0, b1, acc[0][1], 0, 0, 0);
    acc[1][0] = __builtin_amdgcn_mfma_f32_16x16x32_bf16(a1, b0, acc[1][0], 0, 0, 0);
    acc[1][1] = __builtin_amdgcn_mfma_f32_16x16x32_bf16(a1, b1, acc[1][1], 0, 0, 0);
  }

  __shared__ float red[4][32][33];
#pragma unroll
  for (int mi = 0; mi < 2; ++mi)
#pragma unroll
    for (int ni = 0; ni < 2; ++ni)
#pragma unroll
      for (int j = 0; j < 4; ++j)
        red[wid][mi * 16 + lg * 4 + j][ni * 16 + l15] = acc[mi][ni][j];
  __syncthreads();

  int m = threadIdx.x >> 3, b4 = (threadIdx.x & 7) * 4;
#pragma unroll
  for (int k = 0; k < 4; ++k) {
    int bb = b4 + k;
    float s = red[0][m][bb] + red[1][m][bb] + red[2][m][bb] + red[3][m][bb];
    atomicAdd(&hid[(size_t)bb * MH_ + mblk * 32 + m], s);
  }
}

// ---------------------------------------------------------------------------
// K9: decoded = softmax( relu(hid+b_mlp) @ W_dec^T + b_dec ); penal = mean.
// ---------------------------------------------------------------------------
__global__ void k9_out(const float* __restrict__ hid, const float* __restrict__ b_mlp,
                       const float* __restrict__ W_dec, const float* __restrict__ b_dec,
                       const float* __restrict__ penp, float* __restrict__ out) {
  int tid = threadIdx.x;
  if (tid < 64) {
    int b = tid >> 1, c = tid & 1;
    const float* hp = hid + (size_t)b * MH_;
    const float* wp = W_dec + (size_t)c * MH_;
    float acc = b_dec[c];
    for (int k = 0; k < MH_; ++k) {
      float hk = fmaxf(hp[k] + b_mlp[k], 0.f);
      acc = fmaf(hk, wp[k], acc);
    }
    float other = __shfl_xor(acc, 1);
    float mx = fmaxf(acc, other);
    float e = __expf(acc - mx), eo = __expf(other - mx);
    out[b * 2 + c] = e / (e + eo);
  } else if (tid == 64) {
    float s = 0.f;
    for (int b = 0; b < B_; ++b) s += penp[b];
    out[64] = s * (1.f / 32.f);
  }
}

// ---------------------------------------------------------------------------
extern "C" void kernel_launch(void* const* d_in, const int* in_sizes, int n_in,
                              void* d_out, int out_size, void* d_ws, size_t ws_size,
                              hipStream_t stream) {
  const int* inp = (const int*)d_in[0];
  const int* lens = (const int*)d_in[1];
  const float* W_emb = (const float*)d_in[2];
  const float* W_ih = (const float*)d_in[3];
  const float* W_hh = (const float*)d_in[4];
  const float* b_ih = (const float*)d_in[5];
  const float* b_hh = (const float*)d_in[6];
  const float* W1 = (const float*)d_in[7];
  const float* W2 = (const float*)d_in[8];
  const float* W_mlp = (const float*)d_in[9];
  const float* b_mlp = (const float*)d_in[10];
  const float* W_dec = (const float*)d_in[11];
  const float* b_dec = (const float*)d_in[12];
  float* out = (float*)d_out;

  char* ws = (char*)d_ws;
  size_t off = 0;
  auto take = [&](size_t bytes) -> char* {
    char* p = ws + off;
    off = (off + bytes + 255) & ~(size_t)255;
    return p;
  };
  unsigned short* outb = (unsigned short*)take((size_t)B_ * T_ * 2048 * 2);     // 67.1 MB
  unsigned short* hpub = (unsigned short*)take((size_t)2 * T_ * 2 * 16384 * 2); // 67.1 MB
  unsigned short* xb = (unsigned short*)take((size_t)16384 * KE_ * 2);          // 12.6 MB
  unsigned short* wihb = (unsigned short*)take((size_t)8192 * KE_ * 2);         // 6.3 MB
  unsigned short* w1b = (unsigned short*)take((size_t)AC_ * 2048 * 2);          // 1.6 MB
  unsigned short* wmlpb = (unsigned short*)take((size_t)MH_ * FEAT_ * 2);       // 62.9 MB
  unsigned short* th1 = (unsigned short*)take((size_t)16384 * AC_ * 2);         // 12.6 MB
  float* abuf = (float*)take((size_t)B_ * R_ * T_ * 4);                         // 2.0 MB
  unsigned short* mbuf = (unsigned short*)take((size_t)B_ * FEAT_ * 2);         // 3.9 MB
  float* penp = (float*)take(B_ * 4);
  float* hid = (float*)take((size_t)B_ * MH_ * 4);

  if (off > ws_size) {  // unambiguous failure signal: NaN output
    hipMemsetAsync(d_out, 0xFF, (size_t)out_size * 4, stream);
    return;
  }

  // sentinel-init hpub: 0xFFFF bf16 has bit14 set => "unwritten" marker
  hipMemsetAsync(hpub, 0xFF, (size_t)2 * T_ * 2 * 16384 * 2, stream);
  hipMemsetAsync(hid, 0, (size_t)B_ * MH_ * 4, stream);

  k0_prep<<<2048, 256, 0, stream>>>(inp, W_emb, W_ih, W1, W_mlp, xb, wihb, w1b, wmlpb);
  k2_rnn<<<256, 256, 0, stream>>>(W_hh, wihb, xb, b_ih, b_hh, outb, hpub);
  k3_s1<<<512, 256, 0, stream>>>(outb, w1b, th1);
  k4_s2<<<2048, 256, 0, stream>>>(th1, W2, abuf);
  k5_sm<<<240, 256, 0, stream>>>(abuf, lens);
  k6_m<<<512, 256, 0, stream>>>(abuf, outb, mbuf);
  k7_pen<<<32, 256, 0, stream>>>(abuf, penp);
  k8_mlp<<<256, 256, 0, stream>>>(wmlpb, mbuf, hid);
  k9_out<<<1, 128, 0, stream>>>(hid, b_mlp, W_dec, b_dec, penp, out);
}